// Round 2
// baseline (968.741 us; speedup 1.0000x reference)
//
#include <hip/hip_runtime.h>
#include <stdint.h>

typedef unsigned short u16;
typedef __bf16 bf16x8 __attribute__((ext_vector_type(8)));
typedef float f32x4 __attribute__((ext_vector_type(4)));

// ---------- bf16 helpers (raw u16 representation) ----------
__device__ __forceinline__ float bf2f(unsigned u) {
  return __uint_as_float(u << 16);
}
__device__ __forceinline__ u16 f2bf(float f) {
  unsigned x = __float_as_uint(f);
  unsigned r = x + 0x7fffu + ((x >> 16) & 1u);
  return (u16)(r >> 16);
}
__device__ __forceinline__ void unpack8(uint4 v, float* o) {
  o[0] = bf2f(v.x & 0xffff); o[1] = bf2f(v.x >> 16);
  o[2] = bf2f(v.y & 0xffff); o[3] = bf2f(v.y >> 16);
  o[4] = bf2f(v.z & 0xffff); o[5] = bf2f(v.z >> 16);
  o[6] = bf2f(v.w & 0xffff); o[7] = bf2f(v.w >> 16);
}
__device__ __forceinline__ float sigm(float x) { return 1.f / (1.f + __expf(-x)); }
// flag-based input load: f=1 -> buffer holds f32, f=0 -> bf16
__device__ __forceinline__ float ldf(const void* p, size_t i, int f) {
  return f ? ((const float*)p)[i] : bf2f(((const u16*)p)[i]);
}

#define AS1(p) ((const __attribute__((address_space(1))) void*)(p))
#define AS3(p) ((__attribute__((address_space(3))) void*)(p))

#define NC 16384

// =====================================================================
// dtype probe: weights are ~N(0,0.05^2). bf16-interp of true-f32 data has
// ~50% |v|>0.5 (random low-half words); true bf16 has ~0%.
// =====================================================================
__global__ void detect_kernel(const u16* __restrict__ wa1, int* __restrict__ flag) {
  if (threadIdx.x == 0) {
    int cnt = 0;
    for (int i = 0; i < 256; ++i) {
      float v = bf2f(wa1[i]);
      if (fabsf(v) > 0.5f) ++cnt;   // NaN compares false; Inf counts — both fine
    }
    *flag = (cnt > 32) ? 1 : 0;
  }
}

// hid -> canonical bf16 copy (8 elems/thread)
__global__ void cvt_hid_kernel(const void* __restrict__ src, u16* __restrict__ dst,
                               const int* __restrict__ flagp) {
  int i = blockIdx.x * 256 + threadIdx.x;  // 2097152 threads
  if (*flagp) {
    const float4* s = (const float4*)src;
    float4 a = s[(size_t)i * 2], b = s[(size_t)i * 2 + 1];
    union { u16 o[8]; uint4 v; } u;
    u.o[0] = f2bf(a.x); u.o[1] = f2bf(a.y); u.o[2] = f2bf(a.z); u.o[3] = f2bf(a.w);
    u.o[4] = f2bf(b.x); u.o[5] = f2bf(b.y); u.o[6] = f2bf(b.z); u.o[7] = f2bf(b.w);
    ((uint4*)dst)[i] = u.v;
  } else {
    ((uint4*)dst)[i] = ((const uint4*)src)[i];
  }
}

// small tensors -> canonical f32: wealth|W_ih_row512|b_ih|b_hh|Wo|bo  (288256 elems)
__global__ void cvt_small_kernel(const void* wealth, const void* W_ih, const void* b_ih,
                                 const void* b_hh, const void* Wo, const void* bo,
                                 float* __restrict__ dst, const int* __restrict__ flagp) {
  int i = blockIdx.x * 256 + threadIdx.x;
  int f = *flagp;
  const void* src; size_t idx;
  if (i < 16384)       { src = wealth; idx = i; }
  else if (i < 19456)  { src = W_ih;   idx = (size_t)512 * 3072 + (i - 16384); }
  else if (i < 22528)  { src = b_ih;   idx = i - 19456; }
  else if (i < 25600)  { src = b_hh;   idx = i - 22528; }
  else if (i < 287744) { src = Wo;     idx = i - 25600; }
  else                 { src = bo;     idx = i - 287744; }
  dst[i] = ldf(src, idx, f);
}

// =====================================================================
// Generic bf16 MFMA GEMM:  C[m][n] = epi( sum_k A[m][k] * Bt[n][k] )
// m97 structure: 128x128 tile, BK=32, 256 threads, global_load_lds w=16.
// gru mode: per-block K-range from n-region (r/z: full, gin: k<512, ghn: k>=512)
// =====================================================================
__global__ __launch_bounds__(256) void gemm_bt(
    const u16* __restrict__ A0, int lda0, int kbound,
    const u16* __restrict__ A1, int lda1,
    const u16* __restrict__ Bt, int ldb,
    u16* __restrict__ C, int ldc,
    const float* __restrict__ bias, int epi, int Ktot, int gru) {
  __shared__ __align__(16) u16 As[128 * 32];
  __shared__ __align__(16) u16 Bs[128 * 32];
  const int tid = threadIdx.x;
  const int m0 = blockIdx.x * 128;
  const int n0 = blockIdx.y * 128;
  int kbeg = 0, kend = Ktot;
  if (gru) {
    int region = n0 >> 10;
    if (region == 2) kend = 512;
    if (region == 3) kbeg = 512;
  }
  f32x4 acc[4][4] = {};
  const int lane = tid & 63;
  const int w = tid >> 6;
  const int mw = (w & 1) * 64, nw = (w >> 1) * 64;
  const int fr = lane & 15;        // A/B fragment m/n index = lane&15
  const int kq = (lane >> 4) * 8;  // fragment k offset
  const int c0 = tid, c1 = tid + 256;  // 16B staging chunks (512 per tile)
  const int ar0 = c0 >> 2, ak0 = (c0 & 3) * 8;
  const int ar1 = c1 >> 2, ak1 = (c1 & 3) * 8;

  for (int kk = kbeg; kk < kend; kk += 32) {
    const u16* Aseg; int lda, ko;
    if (kk < kbound) { Aseg = A0; lda = lda0; ko = kk; }
    else             { Aseg = A1; lda = lda1; ko = kk - kbound; }
    __syncthreads();
    __builtin_amdgcn_global_load_lds(AS1(Aseg + (size_t)(m0 + ar0) * lda + ko + ak0), AS3(&As[c0 * 8]), 16, 0, 0);
    __builtin_amdgcn_global_load_lds(AS1(Aseg + (size_t)(m0 + ar1) * lda + ko + ak1), AS3(&As[c1 * 8]), 16, 0, 0);
    __builtin_amdgcn_global_load_lds(AS1(Bt + (size_t)(n0 + ar0) * ldb + kk + ak0), AS3(&Bs[c0 * 8]), 16, 0, 0);
    __builtin_amdgcn_global_load_lds(AS1(Bt + (size_t)(n0 + ar1) * ldb + kk + ak1), AS3(&Bs[c1 * 8]), 16, 0, 0);
    __syncthreads();
    bf16x8 af[4], bfv[4];
#pragma unroll
    for (int mt = 0; mt < 4; ++mt)
      af[mt] = *reinterpret_cast<const bf16x8*>(&As[(mw + mt * 16 + fr) * 32 + kq]);
#pragma unroll
    for (int nt = 0; nt < 4; ++nt)
      bfv[nt] = *reinterpret_cast<const bf16x8*>(&Bs[(nw + nt * 16 + fr) * 32 + kq]);
#pragma unroll
    for (int mt = 0; mt < 4; ++mt)
#pragma unroll
      for (int nt = 0; nt < 4; ++nt)
        acc[mt][nt] = __builtin_amdgcn_mfma_f32_16x16x32_bf16(af[mt], bfv[nt], acc[mt][nt], 0, 0, 0);
  }
  // D mapping: col=lane&15, row=(lane>>4)*4+reg  [m89-verified]
  const int rq = (lane >> 4) * 4;
#pragma unroll
  for (int mt = 0; mt < 4; ++mt) {
#pragma unroll
    for (int nt = 0; nt < 4; ++nt) {
      int col = n0 + nw + nt * 16 + (lane & 15);
      f32x4 v = acc[mt][nt];
#pragma unroll
      for (int r = 0; r < 4; ++r) {
        int row = m0 + mw + mt * 16 + rq + r;
        float val = v[r];
        if (epi == 1) { val += bias[col]; val = val > 0.f ? val : 0.f; }
        else if (epi == 2) { val += bias[col]; }
        C[(size_t)row * ldc + col] = f2bf(val);
      }
    }
  }
}

// =====================================================================
// Weight packing (flag-aware raw input reads)
// =====================================================================
__global__ void packW1_kernel(const void* Wa1, const void* Wg1, u16* __restrict__ W1catT,
                              const int* __restrict__ flagp) {
  int idx = blockIdx.x * 256 + threadIdx.x;  // 256*1024
  int f = *flagp;
  int n = idx >> 10, k = idx & 1023;
  float v = (n < 128) ? ldf(Wa1, (size_t)(512 + k) * 128 + n, f)
                      : ldf(Wg1, (size_t)(512 + k) * 128 + (n - 128), f);
  W1catT[idx] = f2bf(v);
}
__global__ void bias1_kernel(const void* x, const void* Wa1, const void* ba1,
                             const void* Wg1, const void* bg1, float* __restrict__ bias1,
                             const int* __restrict__ flagp) {
  int c = threadIdx.x;  // 256
  int f = *flagp;
  const void* W = (c < 128) ? Wa1 : Wg1;
  const void* bb = (c < 128) ? ba1 : bg1;
  int cc = c & 127;
  float acc = ldf(bb, cc, f);
  for (int k = 0; k < 512; ++k) acc += ldf(x, k, f) * ldf(W, (size_t)k * 128 + cc, f);
  bias1[c] = acc;
}
__global__ void packW2_kernel(const void* Wa2, const void* Wg2, u16* __restrict__ W2catT,
                              const int* __restrict__ flagp) {
  int idx = blockIdx.x * 256 + threadIdx.x;  // 512*256
  int f = *flagp;
  int n = idx >> 8, k = idx & 255;
  float v = (k < 128) ? ldf(Wa2, (size_t)k * 512 + n, f)
                      : -ldf(Wg2, (size_t)(k - 128) * 512 + n, f);
  W2catT[idx] = f2bf(v);
}
__global__ void bias2_kernel(const void* ba2, const void* bg2, float* __restrict__ bias2,
                             const int* __restrict__ flagp) {
  int n = blockIdx.x * 256 + threadIdx.x;
  int f = *flagp;
  bias2[n] = ldf(ba2, n, f) - ldf(bg2, n, f);
}
// WgruT[4096][1536]; A-k space: k<512 = output cols, k>=512 = hidden cols
__global__ void packWgru_kernel(const void* W_ih, const void* W_hh, u16* __restrict__ WgruT,
                                const int* __restrict__ flagp) {
  int idx = blockIdx.x * 256 + threadIdx.x;  // 4096*1536
  int f = *flagp;
  int c = idx / 1536, k = idx - c * 1536;
  int region = c >> 10, j = c & 1023;
  float v = 0.f;
  if (region <= 1) {
    int col = (region << 10) + j;
    v = (k < 512) ? ldf(W_ih, (size_t)k * 3072 + col, f)
                  : ldf(W_hh, (size_t)(k - 512) * 3072 + col, f);
  } else if (region == 2) {  // gi_n: only k<512 read
    if (k < 512) v = ldf(W_ih, (size_t)k * 3072 + 2048 + j, f);
  } else {                   // gh_n: only k>=512 read
    if (k >= 512) v = ldf(W_hh, (size_t)(k - 512) * 3072 + 2048 + j, f);
  }
  WgruT[idx] = f2bf(v);
}

// =====================================================================
// tension[i] = mean_c output[i][c]^2  (one wave per row)
// =====================================================================
__global__ void tension_kernel(const u16* __restrict__ outbf, float* __restrict__ tension) {
  int w = threadIdx.x >> 6, lane = threadIdx.x & 63;
  int row = blockIdx.x * 4 + w;
  uint4 v = *reinterpret_cast<const uint4*>(outbf + (size_t)row * 512 + lane * 8);
  float o[8]; unpack8(v, o);
  float s = 0.f;
#pragma unroll
  for (int e = 0; e < 8; ++e) s += o[e] * o[e];
  for (int off = 32; off; off >>= 1) s += __shfl_down(s, off, 64);
  if (lane == 0) tension[row] = s * (1.f / 512.f);
}

// =====================================================================
// GRU gate epilogue -> h_pre (clipped, pre-sync), chunked over rows
// =====================================================================
__global__ void gate_kernel(const u16* __restrict__ pre, const u16* __restrict__ hidc,
                            const float* __restrict__ wihtf, const float* __restrict__ bihf,
                            const float* __restrict__ bhhf, const float* __restrict__ wealthf,
                            const float* __restrict__ tension, u16* __restrict__ hpre,
                            int rowStart) {
  int rl = blockIdx.x, row = rowStart + rl, t = threadIdx.x, j = t * 8;
  const u16* prow = pre + (size_t)rl * 4096;
  float tv = tension[row];
  float wl = fminf(fmaxf(wealthf[row], 0.1f), 2.0f);
  float mod = 0.9f + 0.1f * wl;
  float pr[8], pz[8], pn1[8], pn2[8], hv[8];
  float wtr[8], wtz[8], wtn[8], bir[8], biz[8], bin_[8], bhn[8], bhr4[8], bhz4[8];
  unpack8(*reinterpret_cast<const uint4*>(prow + j), pr);
  unpack8(*reinterpret_cast<const uint4*>(prow + 1024 + j), pz);
  unpack8(*reinterpret_cast<const uint4*>(prow + 2048 + j), pn1);
  unpack8(*reinterpret_cast<const uint4*>(prow + 3072 + j), pn2);
  unpack8(*reinterpret_cast<const uint4*>(hidc + (size_t)row * 1024 + j), hv);
#pragma unroll
  for (int q = 0; q < 2; ++q) {
    *reinterpret_cast<float4*>(&wtr[q * 4]) = *reinterpret_cast<const float4*>(wihtf + j + q * 4);
    *reinterpret_cast<float4*>(&wtz[q * 4]) = *reinterpret_cast<const float4*>(wihtf + 1024 + j + q * 4);
    *reinterpret_cast<float4*>(&wtn[q * 4]) = *reinterpret_cast<const float4*>(wihtf + 2048 + j + q * 4);
    *reinterpret_cast<float4*>(&bir[q * 4]) = *reinterpret_cast<const float4*>(bihf + j + q * 4);
    *reinterpret_cast<float4*>(&biz[q * 4]) = *reinterpret_cast<const float4*>(bihf + 1024 + j + q * 4);
    *reinterpret_cast<float4*>(&bin_[q * 4]) = *reinterpret_cast<const float4*>(bihf + 2048 + j + q * 4);
    *reinterpret_cast<float4*>(&bhr4[q * 4]) = *reinterpret_cast<const float4*>(bhhf + j + q * 4);
    *reinterpret_cast<float4*>(&bhz4[q * 4]) = *reinterpret_cast<const float4*>(bhhf + 1024 + j + q * 4);
    *reinterpret_cast<float4*>(&bhn[q * 4]) = *reinterpret_cast<const float4*>(bhhf + 2048 + j + q * 4);
  }
  union { u16 o[8]; uint4 v; } u;
#pragma unroll
  for (int e = 0; e < 8; ++e) {
    float r = sigm(pr[e] + tv * wtr[e] + bir[e] + bhr4[e]);
    float z = sigm(pz[e] + tv * wtz[e] + biz[e] + bhz4[e]);
    float n = tanhf(pn1[e] + tv * wtn[e] + bin_[e] + r * (pn2[e] + bhn[e]));
    float h2 = (1.f - z) * n + z * hv[e];
    h2 = fminf(fmaxf(h2 * mod, -10.f), 10.f);
    u.o[e] = f2bf(h2);
  }
  *reinterpret_cast<uint4*>(hpre + (size_t)row * 1024 + j) = u.v;
}

__global__ void count_kernel(const int* __restrict__ positions, int* __restrict__ counts) {
  int i = blockIdx.x * 256 + threadIdx.x;
  if (i < NC) {
    int p = positions[i], f = i >> 11;
    if (p > 0) atomicAdd(&counts[f * 2], 1);
    else if (p < 0) atomicAdd(&counts[f * 2 + 1], 1);
  }
}

// per-faction, per-col sums: total / pos>0 / pos<0
__global__ void stats_kernel(const u16* __restrict__ hpre, const int* __restrict__ positions,
                             float* __restrict__ fsums) {
  int cc = blockIdx.x, f = blockIdx.y, t = threadIdx.x;
  int col = cc * 128 + (t & 127);
  int half = t >> 7;
  float st = 0, sp = 0, sm = 0;
  for (int it = 0; it < 1024; ++it) {
    int row = (f << 11) + (it << 1) + half;
    int p = positions[row];
    float v = bf2f(hpre[(size_t)row * 1024 + col]);
    st += v;
    if (p > 0) sp += v;
    if (p < 0) sm += v;
  }
  __shared__ float red[3][256];
  red[0][t] = st; red[1][t] = sp; red[2][t] = sm;
  __syncthreads();
  if (t < 128) {
    fsums[(f * 3 + 0) * 1024 + col] = red[0][t] + red[0][t + 128];
    fsums[(f * 3 + 1) * 1024 + col] = red[1][t] + red[1][t + 128];
    fsums[(f * 3 + 2) * 1024 + col] = red[2][t] + red[2][t + 128];
  }
}

__global__ void derive_kernel(const float* __restrict__ fsums, const int* __restrict__ counts,
                              float* __restrict__ mean1, float* __restrict__ mean2,
                              float* __restrict__ fmean, float* __restrict__ gop,
                              float* __restrict__ scal) {
  int c = threadIdx.x;  // 1024
  int cnt1 = 0, cnt2 = 0, cf1[8], cf2[8];
#pragma unroll
  for (int f = 0; f < 8; ++f) {
    cf1[f] = counts[f * 2]; cf2[f] = counts[f * 2 + 1];
    cnt1 += cf1[f]; cnt2 += cf2[f];
  }
  float s1 = 0, s2 = 0;
#pragma unroll
  for (int f = 0; f < 8; ++f) { s1 += fsums[(f * 3 + 1) * 1024 + c]; s2 += fsums[(f * 3 + 2) * 1024 + c]; }
  float m1 = s1 / (float)(cnt1 > 1 ? cnt1 : 1);
  float m2 = s2 / (float)(cnt2 > 1 ? cnt2 : 1);
  float a1 = (cnt1 >= 2) ? 0.1f : 0.f;
  float a2 = (cnt2 >= 2) ? 0.1f : 0.f;
  float g = 0;
#pragma unroll
  for (int f = 0; f < 8; ++f) {
    float fm = (fsums[(f * 3) * 1024 + c]
                + a1 * ((float)cf1[f] * m1 - fsums[(f * 3 + 1) * 1024 + c])
                + a2 * ((float)cf2[f] * m2 - fsums[(f * 3 + 2) * 1024 + c])) * (1.f / 2048.f);
    fmean[f * 1024 + c] = fm;
    g += fm;
  }
  gop[c] = g * 0.125f;
  mean1[c] = m1; mean2[c] = m2;
  if (c == 0) { scal[0] = a1; scal[1] = a2; }
}

// apply group sync + faction sync + debate; write final new_h (dtype per flag)
__global__ void finalize_kernel(const u16* __restrict__ hpre, const int* __restrict__ positions,
                                const int* __restrict__ step, const float* __restrict__ mean1,
                                const float* __restrict__ mean2, const float* __restrict__ fmean,
                                const float* __restrict__ gop, const float* __restrict__ scal,
                                void* __restrict__ out, const int* __restrict__ flagp) {
  int row = blockIdx.x, t = threadIdx.x, j = t * 8;
  int fl = *flagp;
  int p = positions[row];
  float w1 = (p > 0) ? scal[0] : 0.f;
  float w2 = (p < 0) ? scal[1] : 0.f;
  int f = row >> 11, q = row & 2047;
  bool deb = (step[0] > 5) && (q < 512);
  float hv[8];
  unpack8(*reinterpret_cast<const uint4*>(hpre + (size_t)row * 1024 + j), hv);
  const float* m1p = mean1 + j; const float* m2p = mean2 + j;
  const float* fmp = fmean + f * 1024 + j; const float* gp = gop + j;
  size_t base = 513 + (size_t)row * 1024 + j;
#pragma unroll
  for (int e = 0; e < 8; ++e) {
    float h = hv[e];
    float hgs = h + w1 * (m1p[e] - h) + w2 * (m2p[e] - h);
    float hfs = 0.85f * hgs + 0.15f * fmp[e];
    float hf = deb ? (0.85f * hfs + 0.15f * gp[e]) : hfs;
    if (fl) ((float*)out)[base + e] = hf;
    else    ((u16*)out)[base + e] = f2bf(hf);
  }
}

// softmax over tension + weights + avg_tension (out elem 512)
__global__ void softmax_kernel(const float* __restrict__ tension, float* __restrict__ weights,
                               void* __restrict__ out, const int* __restrict__ flagp) {
  __shared__ float red[1024];
  int t = threadIdx.x;
  float tv[16], mx = -1e30f, sumt = 0.f;
#pragma unroll
  for (int k = 0; k < 16; ++k) {
    tv[k] = tension[t + k * 1024];
    mx = fmaxf(mx, tv[k]); sumt += tv[k];
  }
  red[t] = mx; __syncthreads();
  for (int s = 512; s > 0; s >>= 1) { if (t < s) red[t] = fmaxf(red[t], red[t + s]); __syncthreads(); }
  float m = red[0]; __syncthreads();
  red[t] = sumt; __syncthreads();
  for (int s = 512; s > 0; s >>= 1) { if (t < s) red[t] += red[t + s]; __syncthreads(); }
  float tot = red[0]; __syncthreads();
  float ev[16], se = 0.f;
#pragma unroll
  for (int k = 0; k < 16; ++k) { ev[k] = __expf(tv[k] - m); se += ev[k]; }
  red[t] = se; __syncthreads();
  for (int s = 512; s > 0; s >>= 1) { if (t < s) red[t] += red[t + s]; __syncthreads(); }
  float invS = 1.f / red[0];
#pragma unroll
  for (int k = 0; k < 16; ++k) weights[t + k * 1024] = ev[k] * invS;
  if (t == 0) {
    float av = tot * (1.f / 16384.f);
    if (*flagp) ((float*)out)[512] = av;
    else        ((u16*)out)[512] = f2bf(av);
  }
}

__global__ void wsum_kernel(const float* __restrict__ weights, const u16* __restrict__ outbf,
                            float* __restrict__ co) {
  int b = blockIdx.x, t = threadIdx.x;
  int c = t * 2;
  float a0 = 0.f, a1 = 0.f;
  int i0 = b * 128;
  for (int i = i0; i < i0 + 128; ++i) {
    float w = weights[i];
    unsigned v = *reinterpret_cast<const unsigned*>(outbf + (size_t)i * 512 + c);
    a0 += w * bf2f(v & 0xffff);
    a1 += w * bf2f(v >> 16);
  }
  atomicAdd(&co[c], a0);
  atomicAdd(&co[c + 1], a1);
}

// pred[n] = sum_c co[c]*Wo[c][n] + bo[n]  (out elems 0..511)
__global__ void pred_kernel(const float* __restrict__ co, const float* __restrict__ Wof,
                            const float* __restrict__ bof, void* __restrict__ out,
                            const int* __restrict__ flagp) {
  __shared__ float cs[512];
  int t = threadIdx.x, n = blockIdx.x * 256 + t;
  cs[t] = co[t]; cs[t + 256] = co[t + 256];
  __syncthreads();
  float acc = bof[n];
  for (int ck = 0; ck < 512; ++ck) acc += cs[ck] * Wof[(size_t)ck * 512 + n];
  if (*flagp) ((float*)out)[n] = acc;
  else        ((u16*)out)[n] = f2bf(acc);
}

// =====================================================================
extern "C" void kernel_launch(void* const* d_in, const int* in_sizes, int n_in,
                              void* d_out, int out_size, void* d_ws, size_t ws_size,
                              hipStream_t stream) {
  const void* x        = d_in[0];
  const void* hid      = d_in[1];
  const void* wealth   = d_in[2];
  const void* Wa1      = d_in[3];
  const void* ba1      = d_in[4];
  const void* Wa2      = d_in[5];
  const void* ba2      = d_in[6];
  const void* Wg1      = d_in[7];
  const void* bg1      = d_in[8];
  const void* Wg2      = d_in[9];
  const void* bg2      = d_in[10];
  const void* W_ih     = d_in[11];
  const void* W_hh     = d_in[12];
  const void* b_ih     = d_in[13];
  const void* b_hh     = d_in[14];
  const void* Wo       = d_in[15];
  const void* bo       = d_in[16];
  const int* positions = (const int*)d_in[17];
  const int* step      = (const int*)d_in[18];

  // ---- workspace layout (256B granules) ----
  char* w = (char*)d_ws;
  size_t off = 0;
  auto alloc = [&](size_t bytes) { void* p = w + off; off += (bytes + 255) & ~(size_t)255; return p; };
  u16*   hidc    = (u16*)  alloc((size_t)NC * 1024 * 2); // 33.6 MB canonical bf16 h
  u16*   outbf   = (u16*)  alloc((size_t)NC * 512 * 2);  // 16.8 MB
  u16*   hpre    = (u16*)  alloc((size_t)NC * 1024 * 2); // 33.6 MB
  u16*   WgruT   = (u16*)  alloc((size_t)4096 * 1536 * 2); // 12.6 MB
  u16*   W1catT  = (u16*)  alloc((size_t)256 * 1024 * 2);
  u16*   W2catT  = (u16*)  alloc((size_t)512 * 256 * 2);
  float* bias1   = (float*)alloc(256 * 4);
  float* bias2   = (float*)alloc(512 * 4);
  float* tension = (float*)alloc(NC * 4);
  float* weights = (float*)alloc(NC * 4);
  float* fsums   = (float*)alloc(8 * 3 * 1024 * 4);
  float* mean1   = (float*)alloc(1024 * 4);
  float* mean2   = (float*)alloc(1024 * 4);
  float* gop     = (float*)alloc(1024 * 4);
  float* fmean   = (float*)alloc(8 * 1024 * 4);
  float* scal    = (float*)alloc(8 * 4);
  float* co      = (float*)alloc(512 * 4);   // zeroed
  int*   counts  = (int*)  alloc(16 * 4);    // zeroed (within co+2112)
  int*   flag    = (int*)  alloc(4);         // written by detect_kernel
  float* smallf  = (float*)alloc(288256 * 4); // wealth|wiht|bih|bhh|Wo|bo (f32 canon)
  float* wealthf = smallf;
  float* wihtf   = smallf + 16384;
  float* bihf    = smallf + 19456;
  float* bhhf    = smallf + 22528;
  float* Wof     = smallf + 25600;
  float* bof     = smallf + 287744;
  size_t fixed = off;
  // union region: t1 (MLP hidden) then reused as GRU preact chunk
  size_t t1Bytes = (size_t)NC * 256 * 2;  // 8.4 MB
  size_t avail = ws_size > fixed ? ws_size - fixed : 0;
  int R = 4096;                            // GRU chunk rows
  while (R > 1024 && (size_t)R * 4096 * 2 > avail) R >>= 1;
  size_t uBytes = (size_t)R * 4096 * 2; if (uBytes < t1Bytes) uBytes = t1Bytes;
  u16* t1 = (u16*)alloc(uBytes);
  u16* preact = t1;
  int nch = NC / R;

  hipMemsetAsync(co, 0, 2112, stream);  // co(2048) + counts(64); flag untouched

  detect_kernel<<<1, 64, 0, stream>>>((const u16*)Wa1, flag);
  cvt_hid_kernel<<<8192, 256, 0, stream>>>(hid, hidc, flag);
  cvt_small_kernel<<<1126, 256, 0, stream>>>(wealth, W_ih, b_ih, b_hh, Wo, bo, smallf, flag);

  packW1_kernel<<<1024, 256, 0, stream>>>(Wa1, Wg1, W1catT, flag);
  bias1_kernel<<<1, 256, 0, stream>>>(x, Wa1, ba1, Wg1, bg1, bias1, flag);
  packW2_kernel<<<512, 256, 0, stream>>>(Wa2, Wg2, W2catT, flag);
  bias2_kernel<<<2, 256, 0, stream>>>(ba2, bg2, bias2, flag);
  packWgru_kernel<<<24576, 256, 0, stream>>>(W_ih, W_hh, WgruT, flag);
  count_kernel<<<64, 256, 0, stream>>>(positions, counts);

  // t1 = relu(h @ W1 + bias1)   M=16384 K=1024 N=256
  gemm_bt<<<dim3(128, 2), 256, 0, stream>>>(hidc, 1024, 1024, hidc, 1024,
                                            W1catT, 1024, t1, 256, bias1, 1, 1024, 0);
  // output = t1 @ [Wa2;-Wg2] + (ba2-bg2)   M=16384 K=256 N=512
  gemm_bt<<<dim3(128, 4), 256, 0, stream>>>(t1, 256, 256, t1, 256,
                                            W2catT, 256, outbf, 512, bias2, 2, 256, 0);
  tension_kernel<<<4096, 256, 0, stream>>>(outbf, tension);

  // GRU preacts + gates, chunked over rows (preact reuses t1's region)
  for (int c = 0; c < nch; ++c) {
    const u16* A0 = outbf + (size_t)c * R * 512;
    const u16* A1 = hidc + (size_t)c * R * 1024;
    gemm_bt<<<dim3(R / 128, 32), 256, 0, stream>>>(A0, 512, 512, A1, 1024,
                                                   WgruT, 1536, preact, 4096, nullptr, 0, 1536, 1);
    gate_kernel<<<R, 128, 0, stream>>>(preact, hidc, wihtf, bihf, bhhf, wealthf,
                                       tension, hpre, c * R);
  }

  stats_kernel<<<dim3(8, 8), 256, 0, stream>>>(hpre, positions, fsums);
  derive_kernel<<<1, 1024, 0, stream>>>(fsums, counts, mean1, mean2, fmean, gop, scal);
  finalize_kernel<<<NC, 128, 0, stream>>>(hpre, positions, step, mean1, mean2, fmean, gop,
                                          scal, d_out, flag);

  softmax_kernel<<<1, 1024, 0, stream>>>(tension, weights, d_out, flag);
  wsum_kernel<<<128, 256, 0, stream>>>(weights, outbf, co);
  pred_kernel<<<2, 256, 0, stream>>>(co, Wof, bof, d_out, flag);

  (void)in_sizes; (void)n_in; (void)out_size;
}

// Round 3
// 685.338 us; speedup vs baseline: 1.4135x; 1.4135x over previous
//
#include <hip/hip_runtime.h>
#include <stdint.h>

typedef unsigned short u16;
typedef __bf16 bf16x8 __attribute__((ext_vector_type(8)));
typedef float f32x4 __attribute__((ext_vector_type(4)));

// All float tensors are f32 on device (verified round 2: finalize WRITE_SIZE
// 67 MB = 16.8M elems * 4B). GEMM internals run bf16 MFMA (absmax 0.0156 << 0.05).

__device__ __forceinline__ float bf2f(unsigned u) { return __uint_as_float(u << 16); }
__device__ __forceinline__ u16 f2bf(float f) {
  unsigned x = __float_as_uint(f);
  unsigned r = x + 0x7fffu + ((x >> 16) & 1u);
  return (u16)(r >> 16);
}
__device__ __forceinline__ void unpack8(uint4 v, float* o) {
  o[0] = bf2f(v.x & 0xffff); o[1] = bf2f(v.x >> 16);
  o[2] = bf2f(v.y & 0xffff); o[3] = bf2f(v.y >> 16);
  o[4] = bf2f(v.z & 0xffff); o[5] = bf2f(v.z >> 16);
  o[6] = bf2f(v.w & 0xffff); o[7] = bf2f(v.w >> 16);
}
__device__ __forceinline__ float sigm(float x) { return 1.f / (1.f + __expf(-x)); }

#define AS1(p) ((const __attribute__((address_space(1))) void*)(p))
#define AS3(p) ((__attribute__((address_space(3))) void*)(p))

#define NC 16384

// =====================================================================
// hid f32 -> canonical bf16 (8 elems/thread, fully coalesced)
// =====================================================================
__global__ void cvt_hid_kernel(const float4* __restrict__ src, uint4* __restrict__ dst) {
  int i = blockIdx.x * 256 + threadIdx.x;  // 2,097,152 threads
  float4 a = src[(size_t)i * 2], b = src[(size_t)i * 2 + 1];
  union { u16 o[8]; uint4 v; } u;
  u.o[0] = f2bf(a.x); u.o[1] = f2bf(a.y); u.o[2] = f2bf(a.z); u.o[3] = f2bf(a.w);
  u.o[4] = f2bf(b.x); u.o[5] = f2bf(b.y); u.o[6] = f2bf(b.z); u.o[7] = f2bf(b.w);
  dst[i] = u.v;
}

// =====================================================================
// Generic 64x64 LDS-tiled transpose: dst[row][koff+k] (bf16) = sgn*src[srow0+k][col]
// row = drow0 + col (+ remapAdd if col >= remapThresh). Coalesced both sides.
// =====================================================================
__global__ __launch_bounds__(256) void packT_kernel(
    const float* __restrict__ src, int sld, int srow0,
    u16* __restrict__ dst, int dld, int drow0, int koff,
    int remapThresh, int remapAdd, float sgn) {
  __shared__ float tile[64][65];
  const int k0 = blockIdx.y * 64, c0 = blockIdx.x * 64;
  const int t = threadIdx.x;
  const int tx = t & 15, ty = t >> 4;
#pragma unroll
  for (int p = 0; p < 4; ++p) {
    int r = ty + p * 16;
    float4 v = *reinterpret_cast<const float4*>(&src[(size_t)(srow0 + k0 + r) * sld + c0 + tx * 4]);
    tile[tx * 4 + 0][r] = v.x;
    tile[tx * 4 + 1][r] = v.y;
    tile[tx * 4 + 2][r] = v.z;
    tile[tx * 4 + 3][r] = v.w;
  }
  __syncthreads();
  const int cl = t >> 2;            // col within tile
  const int kb = (t & 3) * 16;      // 16 k per thread
  int col = c0 + cl;
  int row = drow0 + col + ((col >= remapThresh) ? remapAdd : 0);
  union { u16 o[16]; uint4 v[2]; } u;
#pragma unroll
  for (int e = 0; e < 16; ++e) u.o[e] = f2bf(sgn * tile[cl][kb + e]);
  uint4* d = reinterpret_cast<uint4*>(&dst[(size_t)row * dld + koff + k0 + kb]);
  d[0] = u.v[0]; d[1] = u.v[1];
}

// bias1[c] = base + sum_k x[k]*W[k][cc]  (k split over 8 blocks, atomic)
__global__ void bias1_kernel(const float* __restrict__ x, const float* __restrict__ Wa1f,
                             const float* __restrict__ ba1f, const float* __restrict__ Wg1f,
                             const float* __restrict__ bg1f, float* __restrict__ bias1) {
  int c = threadIdx.x;  // 256
  const float* W = (c < 128) ? Wa1f : Wg1f;
  int cc = c & 127;
  float acc = 0.f;
  int k0 = blockIdx.x * 64;
  for (int k = k0; k < k0 + 64; ++k) acc += x[k] * W[(size_t)k * 128 + cc];
  if (blockIdx.x == 0) acc += (c < 128) ? ba1f[cc] : bg1f[cc];
  atomicAdd(&bias1[c], acc);
}
__global__ void bias2_kernel(const float* __restrict__ ba2f, const float* __restrict__ bg2f,
                             float* __restrict__ bias2) {
  int n = blockIdx.x * 256 + threadIdx.x;
  bias2[n] = ba2f[n] - bg2f[n];
}

// =====================================================================
// bf16 MFMA GEMM (m97 structure): C = epi(A @ Bt^T), 128x128 tile, BK=32.
// A split at kbound between A0/A1. gru: region K-range from n-block.
// =====================================================================
__global__ __launch_bounds__(256) void gemm_bt(
    const u16* __restrict__ A0, int lda0, int kbound,
    const u16* __restrict__ A1, int lda1,
    const u16* __restrict__ Bt, int ldb,
    u16* __restrict__ C, int ldc,
    const float* __restrict__ bias, int epi, int Ktot, int gru) {
  __shared__ __align__(16) u16 As[128 * 32];
  __shared__ __align__(16) u16 Bs[128 * 32];
  const int tid = threadIdx.x;
  const int m0 = blockIdx.x * 128;
  const int n0 = blockIdx.y * 128;
  int kbeg = 0, kend = Ktot;
  if (gru) {
    int region = n0 >> 10;
    if (region == 2) kend = 512;   // gi_n: output part only
    if (region == 3) kbeg = 512;   // gh_n: hidden part only
  }
  f32x4 acc[4][4] = {};
  const int lane = tid & 63;
  const int w = tid >> 6;
  const int mw = (w & 1) * 64, nw = (w >> 1) * 64;
  const int fr = lane & 15;
  const int kq = (lane >> 4) * 8;
  const int c0 = tid, c1 = tid + 256;
  const int ar0 = c0 >> 2, ak0 = (c0 & 3) * 8;
  const int ar1 = c1 >> 2, ak1 = (c1 & 3) * 8;

  for (int kk = kbeg; kk < kend; kk += 32) {
    const u16* Aseg; int lda, ko;
    if (kk < kbound) { Aseg = A0; lda = lda0; ko = kk; }
    else             { Aseg = A1; lda = lda1; ko = kk - kbound; }
    __syncthreads();
    __builtin_amdgcn_global_load_lds(AS1(Aseg + (size_t)(m0 + ar0) * lda + ko + ak0), AS3(&As[c0 * 8]), 16, 0, 0);
    __builtin_amdgcn_global_load_lds(AS1(Aseg + (size_t)(m0 + ar1) * lda + ko + ak1), AS3(&As[c1 * 8]), 16, 0, 0);
    __builtin_amdgcn_global_load_lds(AS1(Bt + (size_t)(n0 + ar0) * ldb + kk + ak0), AS3(&Bs[c0 * 8]), 16, 0, 0);
    __builtin_amdgcn_global_load_lds(AS1(Bt + (size_t)(n0 + ar1) * ldb + kk + ak1), AS3(&Bs[c1 * 8]), 16, 0, 0);
    __syncthreads();
    bf16x8 af[4], bfv[4];
#pragma unroll
    for (int mt = 0; mt < 4; ++mt)
      af[mt] = *reinterpret_cast<const bf16x8*>(&As[(mw + mt * 16 + fr) * 32 + kq]);
#pragma unroll
    for (int nt = 0; nt < 4; ++nt)
      bfv[nt] = *reinterpret_cast<const bf16x8*>(&Bs[(nw + nt * 16 + fr) * 32 + kq]);
#pragma unroll
    for (int mt = 0; mt < 4; ++mt)
#pragma unroll
      for (int nt = 0; nt < 4; ++nt)
        acc[mt][nt] = __builtin_amdgcn_mfma_f32_16x16x32_bf16(af[mt], bfv[nt], acc[mt][nt], 0, 0, 0);
  }
  const int rq = (lane >> 4) * 4;  // D: col=lane&15, row=rq+reg [m89]
#pragma unroll
  for (int mt = 0; mt < 4; ++mt) {
#pragma unroll
    for (int nt = 0; nt < 4; ++nt) {
      int col = n0 + nw + nt * 16 + (lane & 15);
      f32x4 v = acc[mt][nt];
#pragma unroll
      for (int r = 0; r < 4; ++r) {
        int row = m0 + mw + mt * 16 + rq + r;
        float val = v[r];
        if (epi == 1) { val += bias[col]; val = val > 0.f ? val : 0.f; }
        else if (epi == 2) { val += bias[col]; }
        C[(size_t)row * ldc + col] = f2bf(val);
      }
    }
  }
}

// =====================================================================
// tension[i] = mean_c output[i][c]^2  (one wave per row)
// =====================================================================
__global__ void tension_kernel(const u16* __restrict__ outbf, float* __restrict__ tension) {
  int w = threadIdx.x >> 6, lane = threadIdx.x & 63;
  int row = blockIdx.x * 4 + w;
  uint4 v = *reinterpret_cast<const uint4*>(outbf + (size_t)row * 512 + lane * 8);
  float o[8]; unpack8(v, o);
  float s = 0.f;
#pragma unroll
  for (int e = 0; e < 8; ++e) s += o[e] * o[e];
  for (int off = 32; off; off >>= 1) s += __shfl_down(s, off, 64);
  if (lane == 0) tension[row] = s * (1.f / 512.f);
}

// =====================================================================
// GRU gate epilogue -> h_pre bf16 (clipped, pre-sync), chunked rows
// =====================================================================
__global__ void gate_kernel(const u16* __restrict__ pre, const u16* __restrict__ hidc,
                            const float* __restrict__ W_ihf, const float* __restrict__ bihf,
                            const float* __restrict__ bhhf, const float* __restrict__ wealthf,
                            const float* __restrict__ tension, u16* __restrict__ hpre,
                            int rowStart) {
  int rl = blockIdx.x, row = rowStart + rl, t = threadIdx.x, j = t * 8;
  const u16* prow = pre + (size_t)rl * 4096;
  const float* wihtf = W_ihf + (size_t)512 * 3072;  // tension row
  float tv = tension[row];
  float wl = fminf(fmaxf(wealthf[row], 0.1f), 2.0f);
  float mod = 0.9f + 0.1f * wl;
  float pr[8], pz[8], pn1[8], pn2[8], hv[8];
  float wtr[8], wtz[8], wtn[8], bir[8], biz[8], bin_[8], bhn[8], bhr4[8], bhz4[8];
  unpack8(*reinterpret_cast<const uint4*>(prow + j), pr);
  unpack8(*reinterpret_cast<const uint4*>(prow + 1024 + j), pz);
  unpack8(*reinterpret_cast<const uint4*>(prow + 2048 + j), pn1);
  unpack8(*reinterpret_cast<const uint4*>(prow + 3072 + j), pn2);
  unpack8(*reinterpret_cast<const uint4*>(hidc + (size_t)row * 1024 + j), hv);
#pragma unroll
  for (int q = 0; q < 2; ++q) {
    *reinterpret_cast<float4*>(&wtr[q * 4]) = *reinterpret_cast<const float4*>(wihtf + j + q * 4);
    *reinterpret_cast<float4*>(&wtz[q * 4]) = *reinterpret_cast<const float4*>(wihtf + 1024 + j + q * 4);
    *reinterpret_cast<float4*>(&wtn[q * 4]) = *reinterpret_cast<const float4*>(wihtf + 2048 + j + q * 4);
    *reinterpret_cast<float4*>(&bir[q * 4]) = *reinterpret_cast<const float4*>(bihf + j + q * 4);
    *reinterpret_cast<float4*>(&biz[q * 4]) = *reinterpret_cast<const float4*>(bihf + 1024 + j + q * 4);
    *reinterpret_cast<float4*>(&bin_[q * 4]) = *reinterpret_cast<const float4*>(bihf + 2048 + j + q * 4);
    *reinterpret_cast<float4*>(&bhr4[q * 4]) = *reinterpret_cast<const float4*>(bhhf + j + q * 4);
    *reinterpret_cast<float4*>(&bhz4[q * 4]) = *reinterpret_cast<const float4*>(bhhf + 1024 + j + q * 4);
    *reinterpret_cast<float4*>(&bhn[q * 4]) = *reinterpret_cast<const float4*>(bhhf + 2048 + j + q * 4);
  }
  union { u16 o[8]; uint4 v; } u;
#pragma unroll
  for (int e = 0; e < 8; ++e) {
    float r = sigm(pr[e] + tv * wtr[e] + bir[e] + bhr4[e]);
    float z = sigm(pz[e] + tv * wtz[e] + biz[e] + bhz4[e]);
    float n = tanhf(pn1[e] + tv * wtn[e] + bin_[e] + r * (pn2[e] + bhn[e]));
    float h2 = (1.f - z) * n + z * hv[e];
    h2 = fminf(fmaxf(h2 * mod, -10.f), 10.f);
    u.o[e] = f2bf(h2);
  }
  *reinterpret_cast<uint4*>(hpre + (size_t)row * 1024 + j) = u.v;
}

__global__ void count_kernel(const int* __restrict__ positions, int* __restrict__ counts) {
  int i = blockIdx.x * 256 + threadIdx.x;
  if (i < NC) {
    int p = positions[i], f = i >> 11;
    if (p > 0) atomicAdd(&counts[f * 2], 1);
    else if (p < 0) atomicAdd(&counts[f * 2 + 1], 1);
  }
}

// per-faction per-col sums (total / pos>0 / pos<0), rows split 8x, atomic
__global__ void stats_kernel(const u16* __restrict__ hpre, const int* __restrict__ positions,
                             float* __restrict__ fsums) {
  int cc = blockIdx.x, f = blockIdx.y, z = blockIdx.z, t = threadIdx.x;
  int col = cc * 128 + (t & 127);
  int half = t >> 7;
  float st = 0, sp = 0, sm = 0;
  for (int it = 0; it < 128; ++it) {
    int row = (f << 11) + ((z * 128 + it) << 1) + half;
    int p = positions[row];
    float v = bf2f(hpre[(size_t)row * 1024 + col]);
    st += v;
    if (p > 0) sp += v;
    if (p < 0) sm += v;
  }
  atomicAdd(&fsums[(f * 3 + 0) * 1024 + col], st);
  atomicAdd(&fsums[(f * 3 + 1) * 1024 + col], sp);
  atomicAdd(&fsums[(f * 3 + 2) * 1024 + col], sm);
}

__global__ void derive_kernel(const float* __restrict__ fsums, const int* __restrict__ counts,
                              float* __restrict__ mean1, float* __restrict__ mean2,
                              float* __restrict__ fmean, float* __restrict__ gop,
                              float* __restrict__ scal) {
  int c = threadIdx.x;  // 1024
  int cnt1 = 0, cnt2 = 0, cf1[8], cf2[8];
#pragma unroll
  for (int f = 0; f < 8; ++f) {
    cf1[f] = counts[f * 2]; cf2[f] = counts[f * 2 + 1];
    cnt1 += cf1[f]; cnt2 += cf2[f];
  }
  float s1 = 0, s2 = 0;
#pragma unroll
  for (int f = 0; f < 8; ++f) { s1 += fsums[(f * 3 + 1) * 1024 + c]; s2 += fsums[(f * 3 + 2) * 1024 + c]; }
  float m1 = s1 / (float)(cnt1 > 1 ? cnt1 : 1);
  float m2 = s2 / (float)(cnt2 > 1 ? cnt2 : 1);
  float a1 = (cnt1 >= 2) ? 0.1f : 0.f;
  float a2 = (cnt2 >= 2) ? 0.1f : 0.f;
  float g = 0;
#pragma unroll
  for (int f = 0; f < 8; ++f) {
    float fm = (fsums[(f * 3) * 1024 + c]
                + a1 * ((float)cf1[f] * m1 - fsums[(f * 3 + 1) * 1024 + c])
                + a2 * ((float)cf2[f] * m2 - fsums[(f * 3 + 2) * 1024 + c])) * (1.f / 2048.f);
    fmean[f * 1024 + c] = fm;
    g += fm;
  }
  gop[c] = g * 0.125f;
  mean1[c] = m1; mean2[c] = m2;
  if (c == 0) { scal[0] = a1; scal[1] = a2; }
}

// group + faction sync + debate; coalesced f32 writes (lane t -> col e*128+t)
__global__ void finalize_kernel(const u16* __restrict__ hpre, const int* __restrict__ positions,
                                const int* __restrict__ step, const float* __restrict__ mean1,
                                const float* __restrict__ mean2, const float* __restrict__ fmean,
                                const float* __restrict__ gop, const float* __restrict__ scal,
                                float* __restrict__ out) {
  int row = blockIdx.x, t = threadIdx.x;
  int p = positions[row];
  float w1 = (p > 0) ? scal[0] : 0.f;
  float w2 = (p < 0) ? scal[1] : 0.f;
  int f = row >> 11, q = row & 2047;
  bool deb = (step[0] > 5) && (q < 512);
  const u16* hrow = hpre + (size_t)row * 1024;
  const float* fmp = fmean + f * 1024;
  float* orow = out + 513 + (size_t)row * 1024;
#pragma unroll
  for (int e = 0; e < 8; ++e) {
    int c = e * 128 + t;
    float h = bf2f(hrow[c]);
    float hgs = h + w1 * (mean1[c] - h) + w2 * (mean2[c] - h);
    float hfs = 0.85f * hgs + 0.15f * fmp[c];
    orow[c] = deb ? (0.85f * hfs + 0.15f * gop[c]) : hfs;
  }
}

// softmax over tension -> weights; avg_tension -> out[512]
__global__ void softmax_kernel(const float* __restrict__ tension, float* __restrict__ weights,
                               float* __restrict__ out) {
  __shared__ float red[1024];
  int t = threadIdx.x;
  float tv[16], mx = -1e30f, sumt = 0.f;
#pragma unroll
  for (int k = 0; k < 16; ++k) {
    tv[k] = tension[t + k * 1024];
    mx = fmaxf(mx, tv[k]); sumt += tv[k];
  }
  red[t] = mx; __syncthreads();
  for (int s = 512; s > 0; s >>= 1) { if (t < s) red[t] = fmaxf(red[t], red[t + s]); __syncthreads(); }
  float m = red[0]; __syncthreads();
  red[t] = sumt; __syncthreads();
  for (int s = 512; s > 0; s >>= 1) { if (t < s) red[t] += red[t + s]; __syncthreads(); }
  float tot = red[0]; __syncthreads();
  float ev[16], se = 0.f;
#pragma unroll
  for (int k = 0; k < 16; ++k) { ev[k] = __expf(tv[k] - m); se += ev[k]; }
  red[t] = se; __syncthreads();
  for (int s = 512; s > 0; s >>= 1) { if (t < s) red[t] += red[t + s]; __syncthreads(); }
  float invS = 1.f / red[0];
#pragma unroll
  for (int k = 0; k < 16; ++k) weights[t + k * 1024] = ev[k] * invS;
  if (t == 0) out[512] = tot * (1.f / 16384.f);
}

__global__ void wsum_kernel(const float* __restrict__ weights, const u16* __restrict__ outbf,
                            float* __restrict__ co) {
  int b = blockIdx.x, t = threadIdx.x;
  int c = t * 2;
  float a0 = 0.f, a1 = 0.f;
  int i0 = b * 128;
  for (int i = i0; i < i0 + 128; ++i) {
    float w = weights[i];
    unsigned v = *reinterpret_cast<const unsigned*>(outbf + (size_t)i * 512 + c);
    a0 += w * bf2f(v & 0xffff);
    a1 += w * bf2f(v >> 16);
  }
  atomicAdd(&co[c], a0);
  atomicAdd(&co[c + 1], a1);
}

// pred[n] = sum_c co[c]*Wo[c][n] + bo[n]  -> out[0..511]
__global__ void pred_kernel(const float* __restrict__ co, const float* __restrict__ Wof,
                            const float* __restrict__ bof, float* __restrict__ out) {
  __shared__ float cs[512];
  int t = threadIdx.x, n = blockIdx.x * 256 + t;
  cs[t] = co[t]; cs[t + 256] = co[t + 256];
  __syncthreads();
  float acc = bof[n];
  for (int ck = 0; ck < 512; ++ck) acc += cs[ck] * Wof[(size_t)ck * 512 + n];
  out[n] = acc;
}

// =====================================================================
extern "C" void kernel_launch(void* const* d_in, const int* in_sizes, int n_in,
                              void* d_out, int out_size, void* d_ws, size_t ws_size,
                              hipStream_t stream) {
  const float* x      = (const float*)d_in[0];
  const float* hid    = (const float*)d_in[1];
  const float* wealth = (const float*)d_in[2];
  const float* Wa1    = (const float*)d_in[3];
  const float* ba1    = (const float*)d_in[4];
  const float* Wa2    = (const float*)d_in[5];
  const float* ba2    = (const float*)d_in[6];
  const float* Wg1    = (const float*)d_in[7];
  const float* bg1    = (const float*)d_in[8];
  const float* Wg2    = (const float*)d_in[9];
  const float* bg2    = (const float*)d_in[10];
  const float* W_ih   = (const float*)d_in[11];
  const float* W_hh   = (const float*)d_in[12];
  const float* b_ih   = (const float*)d_in[13];
  const float* b_hh   = (const float*)d_in[14];
  const float* Wo     = (const float*)d_in[15];
  const float* bo     = (const float*)d_in[16];
  const int* positions= (const int*)d_in[17];
  const int* step     = (const int*)d_in[18];
  float* out = (float*)d_out;  // [0,512) pred | [512] avg_tension | [513..) new_h

  // ---- workspace (256B granules) ----
  char* w = (char*)d_ws;
  size_t off = 0;
  auto alloc = [&](size_t bytes) { void* p = w + off; off += (bytes + 255) & ~(size_t)255; return p; };
  u16*   hidc    = (u16*)  alloc((size_t)NC * 1024 * 2);   // 33.6 MB
  u16*   outbf   = (u16*)  alloc((size_t)NC * 512 * 2);    // 16.8 MB
  u16*   hpre    = (u16*)  alloc((size_t)NC * 1024 * 2);   // 33.6 MB
  u16*   WgruT   = (u16*)  alloc((size_t)4096 * 1536 * 2); // 12.6 MB
  u16*   W1catT  = (u16*)  alloc((size_t)256 * 1024 * 2);
  u16*   W2catT  = (u16*)  alloc((size_t)512 * 256 * 2);
  // zeroed region (contiguous): bias1 | co | counts | fsums
  float* bias1   = (float*)alloc(256 * 4);     // 1024 B
  float* co      = (float*)alloc(512 * 4);     // 2048 B
  int*   counts  = (int*)  alloc(16 * 4);      // 256 B padded
  float* fsums   = (float*)alloc(8 * 3 * 1024 * 4);  // 98304 B
  float* bias2   = (float*)alloc(512 * 4);
  float* tension = (float*)alloc(NC * 4);
  float* weights = (float*)alloc(NC * 4);
  float* mean1   = (float*)alloc(1024 * 4);
  float* mean2   = (float*)alloc(1024 * 4);
  float* gop     = (float*)alloc(1024 * 4);
  float* fmean   = (float*)alloc(8 * 1024 * 4);
  float* scal    = (float*)alloc(8 * 4);
  size_t fixed = off;
  // union: t1 (MLP hidden) reused as GRU preact chunk
  size_t t1Bytes = (size_t)NC * 256 * 2;
  size_t avail = ws_size > fixed ? ws_size - fixed : 0;
  int R = 16384;
  while (R > 1024 && (size_t)R * 4096 * 2 > avail) R >>= 1;
  size_t uBytes = (size_t)R * 4096 * 2; if (uBytes < t1Bytes) uBytes = t1Bytes;
  u16* t1 = (u16*)alloc(uBytes);
  u16* preact = t1;
  int nch = NC / R;

  hipMemsetAsync(bias1, 0, 1024 + 2048 + 256 + 98304, stream);

  cvt_hid_kernel<<<8192, 256, 0, stream>>>((const float4*)hid, (uint4*)hidc);
  // weight packs via tiled transpose (src,sld,srow0, dst,dld,drow0,koff, remapT,remapA, sgn)
  packT_kernel<<<dim3(2, 16), 256, 0, stream>>>(Wa1, 128, 512, W1catT, 1024, 0, 0, 1 << 30, 0, 1.f);
  packT_kernel<<<dim3(2, 16), 256, 0, stream>>>(Wg1, 128, 512, W1catT, 1024, 128, 0, 1 << 30, 0, 1.f);
  packT_kernel<<<dim3(8, 2), 256, 0, stream>>>(Wa2, 512, 0, W2catT, 256, 0, 0, 1 << 30, 0, 1.f);
  packT_kernel<<<dim3(8, 2), 256, 0, stream>>>(Wg2, 512, 0, W2catT, 256, 0, 128, 1 << 30, 0, -1.f);
  packT_kernel<<<dim3(48, 8), 256, 0, stream>>>(W_ih, 3072, 0, WgruT, 1536, 0, 0, 1 << 30, 0, 1.f);
  packT_kernel<<<dim3(48, 16), 256, 0, stream>>>(W_hh, 3072, 0, WgruT, 1536, 0, 512, 2048, 1024, 1.f);
  bias1_kernel<<<8, 256, 0, stream>>>(x, Wa1, ba1, Wg1, bg1, bias1);
  bias2_kernel<<<2, 256, 0, stream>>>(ba2, bg2, bias2);
  count_kernel<<<64, 256, 0, stream>>>(positions, counts);

  // t1 = relu(h @ W1 + bias1)   M=16384 K=1024 N=256
  gemm_bt<<<dim3(128, 2), 256, 0, stream>>>(hidc, 1024, 1024, hidc, 1024,
                                            W1catT, 1024, t1, 256, bias1, 1, 1024, 0);
  // output = t1 @ [Wa2;-Wg2] + (ba2-bg2)   M=16384 K=256 N=512
  gemm_bt<<<dim3(128, 4), 256, 0, stream>>>(t1, 256, 256, t1, 256,
                                            W2catT, 256, outbf, 512, bias2, 2, 256, 0);
  tension_kernel<<<4096, 256, 0, stream>>>(outbf, tension);

  // GRU preacts + gates, chunked (preact reuses t1 region)
  for (int c = 0; c < nch; ++c) {
    const u16* A0 = outbf + (size_t)c * R * 512;
    const u16* A1 = hidc + (size_t)c * R * 1024;
    gemm_bt<<<dim3(R / 128, 32), 256, 0, stream>>>(A0, 512, 512, A1, 1024,
                                                   WgruT, 1536, preact, 4096, nullptr, 0, 1536, 1);
    gate_kernel<<<R, 128, 0, stream>>>(preact, hidc, W_ih, b_ih, b_hh, wealth,
                                       tension, hpre, c * R);
  }

  stats_kernel<<<dim3(8, 8, 8), 256, 0, stream>>>(hpre, positions, fsums);
  derive_kernel<<<1, 1024, 0, stream>>>(fsums, counts, mean1, mean2, fmean, gop, scal);
  finalize_kernel<<<NC, 128, 0, stream>>>(hpre, positions, step, mean1, mean2, fmean, gop,
                                          scal, out);

  softmax_kernel<<<1, 1024, 0, stream>>>(tension, weights, out);
  wsum_kernel<<<128, 256, 0, stream>>>(weights, outbf, co);
  pred_kernel<<<2, 256, 0, stream>>>(co, Wo, bo, out);

  (void)in_sizes; (void)n_in; (void)out_size;
}

// Round 4
// 630.139 us; speedup vs baseline: 1.5373x; 1.0876x over previous
//
#include <hip/hip_runtime.h>
#include <stdint.h>

typedef unsigned short u16;
typedef __bf16 bf16x8 __attribute__((ext_vector_type(8)));
typedef float f32x4 __attribute__((ext_vector_type(4)));

// All float tensors are f32 on device (verified R2: finalize WRITE 67 MB = 16.8M*4B).
// GEMM internals bf16 MFMA (absmax 0.0156 << 0.05 threshold).

__device__ __forceinline__ float bf2f(unsigned u) { return __uint_as_float(u << 16); }
__device__ __forceinline__ u16 f2bf(float f) {
  unsigned x = __float_as_uint(f);
  unsigned r = x + 0x7fffu + ((x >> 16) & 1u);
  return (u16)(r >> 16);
}
__device__ __forceinline__ float sigm(float x) { return 1.f / (1.f + __expf(-x)); }
__device__ __forceinline__ float fast_tanh(float x) {
  float e = __expf(2.f * x);           // large x -> e=inf -> 1-2/inf = 1; x<<0 -> e=0 -> -1
  return 1.f - 2.f / (e + 1.f);
}

#define AS1(p) ((const __attribute__((address_space(1))) void*)(p))
#define AS3(p) ((__attribute__((address_space(3))) void*)(p))

#define NC 16384

// =====================================================================
// Batched prep: job0 = hid f32->bf16 cvt (8192 blocks), jobs 1-6 = 64x64
// LDS-tiled transposes of the 6 weight matrices into packed bf16 layouts.
// One launch instead of 7 (launch-bubble reduction).
// =====================================================================
__device__ __forceinline__ void packT_body(
    const float* __restrict__ src, int sld, int srow0,
    u16* __restrict__ dst, int dld, int drow0, int koff,
    int remapThresh, int remapAdd, float sgn, int bx, int by,
    float (*tile)[65], int t) {
  const int k0 = by * 64, c0 = bx * 64;
  const int tx = t & 15, ty = t >> 4;
#pragma unroll
  for (int p = 0; p < 4; ++p) {
    int r = ty + p * 16;
    float4 v = *reinterpret_cast<const float4*>(&src[(size_t)(srow0 + k0 + r) * sld + c0 + tx * 4]);
    tile[tx * 4 + 0][r] = v.x;
    tile[tx * 4 + 1][r] = v.y;
    tile[tx * 4 + 2][r] = v.z;
    tile[tx * 4 + 3][r] = v.w;
  }
  __syncthreads();
  const int cl = t >> 2;
  const int kb = (t & 3) * 16;
  int col = c0 + cl;
  int row = drow0 + col + ((col >= remapThresh) ? remapAdd : 0);
  union { u16 o[16]; uint4 v[2]; } u;
#pragma unroll
  for (int e = 0; e < 16; ++e) u.o[e] = f2bf(sgn * tile[cl][kb + e]);
  uint4* d = reinterpret_cast<uint4*>(&dst[(size_t)row * dld + koff + k0 + kb]);
  d[0] = u.v[0]; d[1] = u.v[1];
}

__global__ __launch_bounds__(256) void prep_kernel(
    const float* __restrict__ hid, u16* __restrict__ hidc,
    const float* __restrict__ W_ih, const float* __restrict__ W_hh, u16* __restrict__ WgruT,
    const float* __restrict__ Wa1, const float* __restrict__ Wg1, u16* __restrict__ W1catT,
    const float* __restrict__ Wa2, const float* __restrict__ Wg2, u16* __restrict__ W2catT) {
  __shared__ float tile[64][65];
  int b = blockIdx.x, t = threadIdx.x;
  if (b < 8192) {  // cvt: hid f32 -> hidc bf16
    int i = b * 256 + t;
    const float4* s = (const float4*)hid;
    float4 a = s[(size_t)i * 2], c = s[(size_t)i * 2 + 1];
    union { u16 o[8]; uint4 v; } u;
    u.o[0] = f2bf(a.x); u.o[1] = f2bf(a.y); u.o[2] = f2bf(a.z); u.o[3] = f2bf(a.w);
    u.o[4] = f2bf(c.x); u.o[5] = f2bf(c.y); u.o[6] = f2bf(c.z); u.o[7] = f2bf(c.w);
    ((uint4*)hidc)[i] = u.v;
    return;
  }
  b -= 8192;
  if (b < 768) {  // W_hh (1024x3072) -> WgruT cols 512.. ; col>=2048 remaps +1024
    packT_body(W_hh, 3072, 0, WgruT, 1536, 0, 512, 2048, 1024, 1.f, b % 48, b / 48, tile, t);
    return;
  }
  b -= 768;
  if (b < 384) {  // W_ih rows 0..511 (512x3072) -> WgruT cols 0..511
    packT_body(W_ih, 3072, 0, WgruT, 1536, 0, 0, 1 << 30, 0, 1.f, b % 48, b / 48, tile, t);
    return;
  }
  b -= 384;
  if (b < 32) {  // Wa1 hidden part (rows 512..1535, 128 cols) -> W1catT rows 0..127
    packT_body(Wa1, 128, 512, W1catT, 1024, 0, 0, 1 << 30, 0, 1.f, b % 2, b / 2, tile, t);
    return;
  }
  b -= 32;
  if (b < 32) {  // Wg1 -> W1catT rows 128..255
    packT_body(Wg1, 128, 512, W1catT, 1024, 128, 0, 1 << 30, 0, 1.f, b % 2, b / 2, tile, t);
    return;
  }
  b -= 32;
  if (b < 16) {  // Wa2 (128x512) -> W2catT k 0..127
    packT_body(Wa2, 512, 0, W2catT, 256, 0, 0, 1 << 30, 0, 1.f, b % 8, b / 8, tile, t);
    return;
  }
  b -= 16;
  // Wg2 -> W2catT k 128..255, negated
  packT_body(Wg2, 512, 0, W2catT, 256, 0, 128, 1 << 30, 0, -1.f, b % 8, b / 8, tile, t);
}

// =====================================================================
// smalls: bias1 (blocks 0-7), bias2 (8-9), position counts (10-73)
// =====================================================================
__global__ void smalls_kernel(const float* __restrict__ x, const float* __restrict__ Wa1,
                              const float* __restrict__ ba1, const float* __restrict__ Wg1,
                              const float* __restrict__ bg1, float* __restrict__ bias1,
                              const float* __restrict__ ba2, const float* __restrict__ bg2,
                              float* __restrict__ bias2, const int* __restrict__ positions,
                              int* __restrict__ counts) {
  int b = blockIdx.x, t = threadIdx.x;
  if (b < 8) {  // bias1[c] = base + sum_k x[k]*W[k][cc], k-split over 8 blocks
    const float* W = (t < 128) ? Wa1 : Wg1;
    int cc = t & 127;
    float acc = 0.f;
    int k0 = b * 64;
    for (int k = k0; k < k0 + 64; ++k) acc += x[k] * W[(size_t)k * 128 + cc];
    if (b == 0) acc += (t < 128) ? ba1[cc] : bg1[cc];
    atomicAdd(&bias1[t], acc);
  } else if (b < 10) {
    int n = (b - 8) * 256 + t;
    bias2[n] = ba2[n] - bg2[n];
  } else {
    int i = (b - 10) * 256 + t;
    int p = positions[i], f = i >> 11;
    if (p > 0) atomicAdd(&counts[f * 2], 1);
    else if (p < 0) atomicAdd(&counts[f * 2 + 1], 1);
  }
}

// =====================================================================
// bf16 MFMA GEMM (m97 structure): C = epi(A @ Bt^T), 128x128, BK=32.
// epi 1: +bias,relu ; epi 3: +bias, and atomically accumulate per-row
// sum of squares into tension (f32-accurate, pre-bf16-rounding).
// =====================================================================
__global__ __launch_bounds__(256) void gemm_bt(
    const u16* __restrict__ A, int lda,
    const u16* __restrict__ Bt, int ldb,
    u16* __restrict__ C, int ldc,
    const float* __restrict__ bias, int epi, int K,
    float* __restrict__ tension) {
  __shared__ __align__(16) u16 As[128 * 32];
  __shared__ __align__(16) u16 Bs[128 * 32];
  const int tid = threadIdx.x;
  const int m0 = blockIdx.x * 128;
  const int n0 = blockIdx.y * 128;
  f32x4 acc[4][4] = {};
  const int lane = tid & 63;
  const int w = tid >> 6;
  const int mw = (w & 1) * 64, nw = (w >> 1) * 64;
  const int fr = lane & 15;
  const int kq = (lane >> 4) * 8;
  const int ar0 = tid >> 2, ak0 = (tid & 3) * 8;
  const int ar1 = ar0 + 64;

  for (int kk = 0; kk < K; kk += 32) {
    __syncthreads();
    __builtin_amdgcn_global_load_lds(AS1(A + (size_t)(m0 + ar0) * lda + kk + ak0), AS3(&As[tid * 8]), 16, 0, 0);
    __builtin_amdgcn_global_load_lds(AS1(A + (size_t)(m0 + ar1) * lda + kk + ak0), AS3(&As[(tid + 256) * 8]), 16, 0, 0);
    __builtin_amdgcn_global_load_lds(AS1(Bt + (size_t)(n0 + ar0) * ldb + kk + ak0), AS3(&Bs[tid * 8]), 16, 0, 0);
    __builtin_amdgcn_global_load_lds(AS1(Bt + (size_t)(n0 + ar1) * ldb + kk + ak0), AS3(&Bs[(tid + 256) * 8]), 16, 0, 0);
    __syncthreads();
    bf16x8 af[4], bfv[4];
#pragma unroll
    for (int mt = 0; mt < 4; ++mt)
      af[mt] = *reinterpret_cast<const bf16x8*>(&As[(mw + mt * 16 + fr) * 32 + kq]);
#pragma unroll
    for (int nt = 0; nt < 4; ++nt)
      bfv[nt] = *reinterpret_cast<const bf16x8*>(&Bs[(nw + nt * 16 + fr) * 32 + kq]);
#pragma unroll
    for (int mt = 0; mt < 4; ++mt)
#pragma unroll
      for (int nt = 0; nt < 4; ++nt)
        acc[mt][nt] = __builtin_amdgcn_mfma_f32_16x16x32_bf16(af[mt], bfv[nt], acc[mt][nt], 0, 0, 0);
  }
  const int rq = (lane >> 4) * 4;  // D: col=lane&15, row=rq+reg [m89]
#pragma unroll
  for (int mt = 0; mt < 4; ++mt) {
    float srow[4] = {0.f, 0.f, 0.f, 0.f};
#pragma unroll
    for (int nt = 0; nt < 4; ++nt) {
      int col = n0 + nw + nt * 16 + fr;
      f32x4 v = acc[mt][nt];
#pragma unroll
      for (int r = 0; r < 4; ++r) {
        int row = m0 + mw + mt * 16 + rq + r;
        float val = v[r] + bias[col];
        if (epi == 1) val = val > 0.f ? val : 0.f;
        else srow[r] += val * val;
        C[(size_t)row * ldc + col] = f2bf(val);
      }
    }
    if (epi == 3) {
#pragma unroll
      for (int r = 0; r < 4; ++r) {
        float s = srow[r];
        s += __shfl_xor(s, 1, 16); s += __shfl_xor(s, 2, 16);
        s += __shfl_xor(s, 4, 16); s += __shfl_xor(s, 8, 16);
        if (fr == 0) atomicAdd(&tension[m0 + mw + mt * 16 + rq + r], s);
      }
    }
  }
}

// =====================================================================
// Fused GRU: preactivations (4 regions r/z/gi_n/gh_n) + gate math + mod/clip
// -> hpre bf16, no preact materialization.
// Block: 128 rows x 64 hidden cols. K-loop over 1536 (out 512 | hid 1024).
// gi_n gated to k<512, gh_n to k>=512 -> 3 B tiles staged per iter.
// =====================================================================
__global__ __launch_bounds__(256, 2) void gemm_gru(
    const u16* __restrict__ outbf, const u16* __restrict__ hidc,
    const u16* __restrict__ WgruT,
    const float* __restrict__ W_ihf, const float* __restrict__ bihf,
    const float* __restrict__ bhhf, const float* __restrict__ wealthf,
    const float* __restrict__ tension, u16* __restrict__ hpre) {
  __shared__ __align__(16) u16 As[128 * 32];
  __shared__ __align__(16) u16 Bs[3][64 * 32];
  const int tid = threadIdx.x;
  const int m0 = blockIdx.x * 128;
  const int j0 = blockIdx.y * 64;
  f32x4 acc[4][4][2] = {};  // [region][mt][nt]
  const int lane = tid & 63;
  const int w = tid >> 6;
  const int mw = (w & 1) * 64, nw = (w >> 1) * 32;
  const int fr = lane & 15;
  const int kq = (lane >> 4) * 8;
  const int ar0 = tid >> 2, ak0 = (tid & 3) * 8;
  const int ar1 = ar0 + 64;

  auto kstep = [&](const u16* Ap, int lda, int ka, int growBase, int gi) {
    __syncthreads();
    __builtin_amdgcn_global_load_lds(AS1(Ap + (size_t)(m0 + ar0) * lda + ka + ak0), AS3(&As[tid * 8]), 16, 0, 0);
    __builtin_amdgcn_global_load_lds(AS1(Ap + (size_t)(m0 + ar1) * lda + ka + ak0), AS3(&As[(tid + 256) * 8]), 16, 0, 0);
    // kk (global K coord) for B cols = ka for out-part, ka+512 for hid-part; caller bakes it
    (void)growBase; (void)gi;
  };
  (void)kstep;

  // --- phase 1: k = 0..511 (A = outbf, gated region = gi_n -> acc[2]) ---
  // --- phase 2: k = 512..1535 (A = hidc, gated region = gh_n -> acc[3]) ---
#pragma unroll 1
  for (int phase = 0; phase < 2; ++phase) {
    const u16* Ap = phase ? hidc : outbf;
    const int lda = phase ? 1024 : 512;
    const int kbeg = phase ? 512 : 0;
    const int kend = phase ? 1536 : 512;
    const int growG = phase ? 3072 : 2048;  // gated B row base
#pragma unroll 1
    for (int kk = kbeg; kk < kend; kk += 32) {
      __syncthreads();
      int ka = kk - kbeg;
      __builtin_amdgcn_global_load_lds(AS1(Ap + (size_t)(m0 + ar0) * lda + ka + ak0), AS3(&As[tid * 8]), 16, 0, 0);
      __builtin_amdgcn_global_load_lds(AS1(Ap + (size_t)(m0 + ar1) * lda + ka + ak0), AS3(&As[(tid + 256) * 8]), 16, 0, 0);
      __builtin_amdgcn_global_load_lds(AS1(WgruT + (size_t)(j0 + ar0) * 1536 + kk + ak0), AS3(&Bs[0][tid * 8]), 16, 0, 0);
      __builtin_amdgcn_global_load_lds(AS1(WgruT + (size_t)(1024 + j0 + ar0) * 1536 + kk + ak0), AS3(&Bs[1][tid * 8]), 16, 0, 0);
      __builtin_amdgcn_global_load_lds(AS1(WgruT + (size_t)(growG + j0 + ar0) * 1536 + kk + ak0), AS3(&Bs[2][tid * 8]), 16, 0, 0);
      __syncthreads();
      bf16x8 af[4], b0[2], b1[2], b2[2];
#pragma unroll
      for (int mt = 0; mt < 4; ++mt)
        af[mt] = *reinterpret_cast<const bf16x8*>(&As[(mw + mt * 16 + fr) * 32 + kq]);
#pragma unroll
      for (int nt = 0; nt < 2; ++nt) {
        b0[nt] = *reinterpret_cast<const bf16x8*>(&Bs[0][(nw + nt * 16 + fr) * 32 + kq]);
        b1[nt] = *reinterpret_cast<const bf16x8*>(&Bs[1][(nw + nt * 16 + fr) * 32 + kq]);
        b2[nt] = *reinterpret_cast<const bf16x8*>(&Bs[2][(nw + nt * 16 + fr) * 32 + kq]);
      }
      int greg = phase ? 3 : 2;
#pragma unroll
      for (int mt = 0; mt < 4; ++mt)
#pragma unroll
        for (int nt = 0; nt < 2; ++nt) {
          acc[0][mt][nt] = __builtin_amdgcn_mfma_f32_16x16x32_bf16(af[mt], b0[nt], acc[0][mt][nt], 0, 0, 0);
          acc[1][mt][nt] = __builtin_amdgcn_mfma_f32_16x16x32_bf16(af[mt], b1[nt], acc[1][mt][nt], 0, 0, 0);
          acc[greg][mt][nt] = __builtin_amdgcn_mfma_f32_16x16x32_bf16(af[mt], b2[nt], acc[greg][mt][nt], 0, 0, 0);
        }
    }
  }

  // --- epilogue: GRU gate math, D mapping col=lane&15, row=(lane>>4)*4+reg ---
  const int rq = (lane >> 4) * 4;
  const float* wt = W_ihf + (size_t)512 * 3072;  // tension row of W_ih
  float wtr[2], wtz[2], wtn[2], bir[2], biz[2], bin_[2], bhr_[2], bhz_[2], bhn_[2];
#pragma unroll
  for (int nt = 0; nt < 2; ++nt) {
    int j = j0 + nw + nt * 16 + fr;
    wtr[nt] = wt[j]; wtz[nt] = wt[1024 + j]; wtn[nt] = wt[2048 + j];
    bir[nt] = bihf[j]; biz[nt] = bihf[1024 + j]; bin_[nt] = bihf[2048 + j];
    bhr_[nt] = bhhf[j]; bhz_[nt] = bhhf[1024 + j]; bhn_[nt] = bhhf[2048 + j];
  }
#pragma unroll
  for (int mt = 0; mt < 4; ++mt) {
#pragma unroll
    for (int rr = 0; rr < 4; ++rr) {
      int row = m0 + mw + mt * 16 + rq + rr;
      float tv = tension[row] * (1.f / 512.f);
      float wl = fminf(fmaxf(wealthf[row], 0.1f), 2.0f);
      float mod = 0.9f + 0.1f * wl;
#pragma unroll
      for (int nt = 0; nt < 2; ++nt) {
        int j = j0 + nw + nt * 16 + fr;
        float r = sigm(acc[0][mt][nt][rr] + tv * wtr[nt] + bir[nt] + bhr_[nt]);
        float z = sigm(acc[1][mt][nt][rr] + tv * wtz[nt] + biz[nt] + bhz_[nt]);
        float n = fast_tanh(acc[2][mt][nt][rr] + tv * wtn[nt] + bin_[nt]
                            + r * (acc[3][mt][nt][rr] + bhn_[nt]));
        float h = bf2f(hidc[(size_t)row * 1024 + j]);
        float h2 = (1.f - z) * n + z * h;
        h2 = fminf(fmaxf(h2 * mod, -10.f), 10.f);
        hpre[(size_t)row * 1024 + j] = f2bf(h2);
      }
    }
  }
}

// =====================================================================
// per-faction per-col sums (total / pos>0 / pos<0), rows split 8x, atomic
// =====================================================================
__global__ void stats_kernel(const u16* __restrict__ hpre, const int* __restrict__ positions,
                             float* __restrict__ fsums) {
  int cc = blockIdx.x, f = blockIdx.y, z = blockIdx.z, t = threadIdx.x;
  int col = cc * 128 + (t & 127);
  int half = t >> 7;
  float st = 0, sp = 0, sm = 0;
  for (int it = 0; it < 128; ++it) {
    int row = (f << 11) + ((z * 128 + it) << 1) + half;
    int p = positions[row];
    float v = bf2f(hpre[(size_t)row * 1024 + col]);
    st += v;
    if (p > 0) sp += v;
    if (p < 0) sm += v;
  }
  atomicAdd(&fsums[(f * 3 + 0) * 1024 + col], st);
  atomicAdd(&fsums[(f * 3 + 1) * 1024 + col], sp);
  atomicAdd(&fsums[(f * 3 + 2) * 1024 + col], sm);
}

__global__ void derive_kernel(const float* __restrict__ fsums, const int* __restrict__ counts,
                              float* __restrict__ mean1, float* __restrict__ mean2,
                              float* __restrict__ fmean, float* __restrict__ gop,
                              float* __restrict__ scal) {
  int c = threadIdx.x;  // 1024
  int cnt1 = 0, cnt2 = 0, cf1[8], cf2[8];
#pragma unroll
  for (int f = 0; f < 8; ++f) {
    cf1[f] = counts[f * 2]; cf2[f] = counts[f * 2 + 1];
    cnt1 += cf1[f]; cnt2 += cf2[f];
  }
  float s1 = 0, s2 = 0;
#pragma unroll
  for (int f = 0; f < 8; ++f) { s1 += fsums[(f * 3 + 1) * 1024 + c]; s2 += fsums[(f * 3 + 2) * 1024 + c]; }
  float m1 = s1 / (float)(cnt1 > 1 ? cnt1 : 1);
  float m2 = s2 / (float)(cnt2 > 1 ? cnt2 : 1);
  float a1 = (cnt1 >= 2) ? 0.1f : 0.f;
  float a2 = (cnt2 >= 2) ? 0.1f : 0.f;
  float g = 0;
#pragma unroll
  for (int f = 0; f < 8; ++f) {
    float fm = (fsums[(f * 3) * 1024 + c]
                + a1 * ((float)cf1[f] * m1 - fsums[(f * 3 + 1) * 1024 + c])
                + a2 * ((float)cf2[f] * m2 - fsums[(f * 3 + 2) * 1024 + c])) * (1.f / 2048.f);
    fmean[f * 1024 + c] = fm;
    g += fm;
  }
  gop[c] = g * 0.125f;
  mean1[c] = m1; mean2[c] = m2;
  if (c == 0) { scal[0] = a1; scal[1] = a2; }
}

// group + faction sync + debate; coalesced f32 writes (lane t -> col e*128+t)
__global__ void finalize_kernel(const u16* __restrict__ hpre, const int* __restrict__ positions,
                                const int* __restrict__ step, const float* __restrict__ mean1,
                                const float* __restrict__ mean2, const float* __restrict__ fmean,
                                const float* __restrict__ gop, const float* __restrict__ scal,
                                float* __restrict__ out) {
  int row = blockIdx.x, t = threadIdx.x;
  int p = positions[row];
  float w1 = (p > 0) ? scal[0] : 0.f;
  float w2 = (p < 0) ? scal[1] : 0.f;
  int f = row >> 11, q = row & 2047;
  bool deb = (step[0] > 5) && (q < 512);
  const u16* hrow = hpre + (size_t)row * 1024;
  const float* fmp = fmean + f * 1024;
  float* orow = out + 513 + (size_t)row * 1024;
#pragma unroll
  for (int e = 0; e < 8; ++e) {
    int c = e * 128 + t;
    float h = bf2f(hrow[c]);
    float hgs = h + w1 * (mean1[c] - h) + w2 * (mean2[c] - h);
    float hfs = 0.85f * hgs + 0.15f * fmp[c];
    orow[c] = deb ? (0.85f * hfs + 0.15f * gop[c]) : hfs;
  }
}

// softmax over tension (raw sum-of-squares; scale 1/512) -> weights; avg -> out[512]
__global__ void softmax_kernel(const float* __restrict__ tension, float* __restrict__ weights,
                               float* __restrict__ out) {
  __shared__ float red[1024];
  int t = threadIdx.x;
  float tv[16], mx = -1e30f, sumt = 0.f;
#pragma unroll
  for (int k = 0; k < 16; ++k) {
    tv[k] = tension[t + k * 1024] * (1.f / 512.f);
    mx = fmaxf(mx, tv[k]); sumt += tv[k];
  }
  red[t] = mx; __syncthreads();
  for (int s = 512; s > 0; s >>= 1) { if (t < s) red[t] = fmaxf(red[t], red[t + s]); __syncthreads(); }
  float m = red[0]; __syncthreads();
  red[t] = sumt; __syncthreads();
  for (int s = 512; s > 0; s >>= 1) { if (t < s) red[t] += red[t + s]; __syncthreads(); }
  float tot = red[0]; __syncthreads();
  float ev[16], se = 0.f;
#pragma unroll
  for (int k = 0; k < 16; ++k) { ev[k] = __expf(tv[k] - m); se += ev[k]; }
  red[t] = se; __syncthreads();
  for (int s = 512; s > 0; s >>= 1) { if (t < s) red[t] += red[t + s]; __syncthreads(); }
  float invS = 1.f / red[0];
#pragma unroll
  for (int k = 0; k < 16; ++k) weights[t + k * 1024] = ev[k] * invS;
  if (t == 0) out[512] = tot * (1.f / 16384.f);
}

__global__ void wsum_kernel(const float* __restrict__ weights, const u16* __restrict__ outbf,
                            float* __restrict__ co) {
  int b = blockIdx.x, t = threadIdx.x;
  int c = t * 2;
  float a0 = 0.f, a1 = 0.f;
  int i0 = b * 128;
  for (int i = i0; i < i0 + 128; ++i) {
    float w = weights[i];
    unsigned v = *reinterpret_cast<const unsigned*>(outbf + (size_t)i * 512 + c);
    a0 += w * bf2f(v & 0xffff);
    a1 += w * bf2f(v >> 16);
  }
  atomicAdd(&co[c], a0);
  atomicAdd(&co[c + 1], a1);
}

__global__ void pred_kernel(const float* __restrict__ co, const float* __restrict__ Wof,
                            const float* __restrict__ bof, float* __restrict__ out) {
  __shared__ float cs[512];
  int t = threadIdx.x, n = blockIdx.x * 256 + t;
  cs[t] = co[t]; cs[t + 256] = co[t + 256];
  __syncthreads();
  float acc = bof[n];
  for (int ck = 0; ck < 512; ++ck) acc += cs[ck] * Wof[(size_t)ck * 512 + n];
  out[n] = acc;
}

// =====================================================================
extern "C" void kernel_launch(void* const* d_in, const int* in_sizes, int n_in,
                              void* d_out, int out_size, void* d_ws, size_t ws_size,
                              hipStream_t stream) {
  const float* x      = (const float*)d_in[0];
  const float* hid    = (const float*)d_in[1];
  const float* wealth = (const float*)d_in[2];
  const float* Wa1    = (const float*)d_in[3];
  const float* ba1    = (const float*)d_in[4];
  const float* Wa2    = (const float*)d_in[5];
  const float* ba2    = (const float*)d_in[6];
  const float* Wg1    = (const float*)d_in[7];
  const float* bg1    = (const float*)d_in[8];
  const float* Wg2    = (const float*)d_in[9];
  const float* bg2    = (const float*)d_in[10];
  const float* W_ih   = (const float*)d_in[11];
  const float* W_hh   = (const float*)d_in[12];
  const float* b_ih   = (const float*)d_in[13];
  const float* b_hh   = (const float*)d_in[14];
  const float* Wo     = (const float*)d_in[15];
  const float* bo     = (const float*)d_in[16];
  const int* positions= (const int*)d_in[17];
  const int* step     = (const int*)d_in[18];
  float* out = (float*)d_out;  // [0,512) pred | [512] avg_tension | [513..) new_h

  char* w = (char*)d_ws;
  size_t off = 0;
  auto alloc = [&](size_t bytes) { void* p = w + off; off += (bytes + 255) & ~(size_t)255; return p; };
  u16*   hidc    = (u16*)  alloc((size_t)NC * 1024 * 2);   // 33.6 MB
  u16*   outbf   = (u16*)  alloc((size_t)NC * 512 * 2);    // 16.8 MB
  u16*   hpre    = (u16*)  alloc((size_t)NC * 1024 * 2);   // 33.6 MB
  u16*   WgruT   = (u16*)  alloc((size_t)4096 * 1536 * 2); // 12.6 MB
  u16*   W1catT  = (u16*)  alloc((size_t)256 * 1024 * 2);
  u16*   W2catT  = (u16*)  alloc((size_t)512 * 256 * 2);
  u16*   t1      = (u16*)  alloc((size_t)NC * 256 * 2);    // 8.4 MB
  // zeroed contiguous run: bias1 | co | counts | fsums | tension
  float* bias1   = (float*)alloc(256 * 4);                 // 1024
  float* co      = (float*)alloc(512 * 4);                 // 2048
  int*   counts  = (int*)  alloc(16 * 4);                  // 256 padded
  float* fsums   = (float*)alloc(8 * 3 * 1024 * 4);        // 98304
  float* tension = (float*)alloc(NC * 4);                  // 65536
  float* bias2   = (float*)alloc(512 * 4);
  float* weights = (float*)alloc(NC * 4);
  float* mean1   = (float*)alloc(1024 * 4);
  float* mean2   = (float*)alloc(1024 * 4);
  float* gop     = (float*)alloc(1024 * 4);
  float* fmean   = (float*)alloc(8 * 1024 * 4);
  float* scal    = (float*)alloc(8 * 4);

  hipMemsetAsync(bias1, 0, 1024 + 2048 + 256 + 98304 + 65536, stream);

  // prep: cvt_hid (8192) + W_hh (768) + W_ih (384) + Wa1/Wg1 (64) + Wa2/Wg2 (32)
  prep_kernel<<<9440, 256, 0, stream>>>(hid, hidc, W_ih, W_hh, WgruT,
                                        Wa1, Wg1, W1catT, Wa2, Wg2, W2catT);
  smalls_kernel<<<74, 256, 0, stream>>>(x, Wa1, ba1, Wg1, bg1, bias1,
                                        ba2, bg2, bias2, positions, counts);

  // t1 = relu(h @ W1 + bias1)   M=16384 K=1024 N=256
  gemm_bt<<<dim3(128, 2), 256, 0, stream>>>(hidc, 1024, W1catT, 1024, t1, 256,
                                            bias1, 1, 1024, nullptr);
  // output = t1 @ [Wa2;-Wg2] + (ba2-bg2); fused tension sum-of-squares
  gemm_bt<<<dim3(128, 4), 256, 0, stream>>>(t1, 256, W2catT, 256, outbf, 512,
                                            bias2, 3, 256, tension);

  // fused GRU: preacts + gates -> hpre (128x64 tiles, 2048 blocks)
  gemm_gru<<<dim3(128, 16), 256, 0, stream>>>(outbf, hidc, WgruT, W_ih, b_ih, b_hh,
                                              wealth, tension, hpre);

  stats_kernel<<<dim3(8, 8, 8), 256, 0, stream>>>(hpre, positions, fsums);
  derive_kernel<<<1, 1024, 0, stream>>>(fsums, counts, mean1, mean2, fmean, gop, scal);
  finalize_kernel<<<NC, 128, 0, stream>>>(hpre, positions, step, mean1, mean2, fmean, gop,
                                          scal, out);

  softmax_kernel<<<1, 1024, 0, stream>>>(tension, weights, out);
  wsum_kernel<<<128, 256, 0, stream>>>(weights, outbf, co);
  pred_kernel<<<2, 256, 0, stream>>>(co, Wo, bo, out);

  (void)in_sizes; (void)n_in; (void)out_size; (void)ws_size;
}

// Round 5
// 604.428 us; speedup vs baseline: 1.6027x; 1.0425x over previous
//
#include <hip/hip_runtime.h>
#include <stdint.h>

typedef unsigned short u16;
typedef __bf16 bf16x8 __attribute__((ext_vector_type(8)));
typedef float f32x4 __attribute__((ext_vector_type(4)));

// f32 inputs/outputs (verified R2). GEMMs run bf16 MFMA (absmax 0.0156 << 0.05).
// R4 lessons: (1) dynamic acc index forced by un-unrolled phase loop, (2) 8-way
// LDS conflicts from row*32+kq layout, (3) 2 blocks/CU occupancy cap.

__device__ __forceinline__ float bf2f(unsigned u) { return __uint_as_float(u << 16); }
__device__ __forceinline__ u16 f2bf(float f) {
  unsigned x = __float_as_uint(f);
  unsigned r = x + 0x7fffu + ((x >> 16) & 1u);
  return (u16)(r >> 16);
}
__device__ __forceinline__ unsigned pack2(float a, float b) {
  return (unsigned)f2bf(a) | ((unsigned)f2bf(b) << 16);
}
__device__ __forceinline__ float sigm(float x) { return 1.f / (1.f + __expf(-x)); }
__device__ __forceinline__ float fast_tanh(float x) {
  float e = __expf(2.f * x);
  return 1.f - 2.f / (e + 1.f);
}

#define AS1(p) ((const __attribute__((address_space(1))) void*)(p))
#define AS3(p) ((__attribute__((address_space(3))) void*)(p))

#define NC 16384

// =====================================================================
// prep: [0,16384) hid f32->bf16 cvt ; [16384,17632) weight transposes ;
// [17632,17706) smalls (bias1/bias2/counts). One launch.
// =====================================================================
__device__ __forceinline__ void packT_body(
    const float* __restrict__ src, int sld, int srow0,
    u16* __restrict__ dst, int dld, int drow0, int koff,
    int remapThresh, int remapAdd, float sgn, int bx, int by,
    float (*tile)[65], int t) {
  const int k0 = by * 64, c0 = bx * 64;
  const int tx = t & 15, ty = t >> 4;
#pragma unroll
  for (int p = 0; p < 4; ++p) {
    int r = ty + p * 16;
    float4 v = *reinterpret_cast<const float4*>(&src[(size_t)(srow0 + k0 + r) * sld + c0 + tx * 4]);
    tile[tx * 4 + 0][r] = v.x;
    tile[tx * 4 + 1][r] = v.y;
    tile[tx * 4 + 2][r] = v.z;
    tile[tx * 4 + 3][r] = v.w;
  }
  __syncthreads();
  const int cl = t >> 2;
  const int kb = (t & 3) * 16;
  int col = c0 + cl;
  int row = drow0 + col + ((col >= remapThresh) ? remapAdd : 0);
  union { u16 o[16]; uint4 v[2]; } u;
#pragma unroll
  for (int e = 0; e < 16; ++e) u.o[e] = f2bf(sgn * tile[cl][kb + e]);
  uint4* d = reinterpret_cast<uint4*>(&dst[(size_t)row * dld + koff + k0 + kb]);
  d[0] = u.v[0]; d[1] = u.v[1];
}

__global__ __launch_bounds__(256) void prep_kernel(
    const float* __restrict__ hid, u16* __restrict__ hidc,
    const float* __restrict__ W_ih, const float* __restrict__ W_hh, u16* __restrict__ WgruT,
    const float* __restrict__ Wa1, const float* __restrict__ Wg1, u16* __restrict__ W1catT,
    const float* __restrict__ Wa2, const float* __restrict__ Wg2, u16* __restrict__ W2catT,
    const float* __restrict__ x, const float* __restrict__ ba1, const float* __restrict__ bg1,
    float* __restrict__ bias1, const float* __restrict__ ba2, const float* __restrict__ bg2,
    float* __restrict__ bias2, const int* __restrict__ positions, int* __restrict__ counts) {
  __shared__ float tile[64][65];
  int b = blockIdx.x, t = threadIdx.x;
  if (b < 16384) {  // cvt: 4 f32 -> 4 bf16 per thread, fully coalesced
    int i = b * 256 + t;
    float4 v = ((const float4*)hid)[i];
    uint2 o; o.x = pack2(v.x, v.y); o.y = pack2(v.z, v.w);
    ((uint2*)hidc)[i] = o;
    return;
  }
  b -= 16384;
  if (b < 768) {  // W_hh (1024x3072) -> WgruT cols 512..; col>=2048 remaps +1024
    packT_body(W_hh, 3072, 0, WgruT, 1536, 0, 512, 2048, 1024, 1.f, b % 48, b / 48, tile, t);
    return;
  }
  b -= 768;
  if (b < 384) {  // W_ih rows 0..511 -> WgruT cols 0..511
    packT_body(W_ih, 3072, 0, WgruT, 1536, 0, 0, 1 << 30, 0, 1.f, b % 48, b / 48, tile, t);
    return;
  }
  b -= 384;
  if (b < 32) { packT_body(Wa1, 128, 512, W1catT, 1024, 0, 0, 1 << 30, 0, 1.f, b % 2, b / 2, tile, t); return; }
  b -= 32;
  if (b < 32) { packT_body(Wg1, 128, 512, W1catT, 1024, 128, 0, 1 << 30, 0, 1.f, b % 2, b / 2, tile, t); return; }
  b -= 32;
  if (b < 16) { packT_body(Wa2, 512, 0, W2catT, 256, 0, 0, 1 << 30, 0, 1.f, b % 8, b / 8, tile, t); return; }
  b -= 16;
  if (b < 16) { packT_body(Wg2, 512, 0, W2catT, 256, 0, 128, 1 << 30, 0, -1.f, b % 8, b / 8, tile, t); return; }
  b -= 16;
  if (b < 8) {  // bias1, k-split over 8 blocks, atomic into zeroed buf
    const float* W = (t < 128) ? Wa1 : Wg1;
    int cc = t & 127;
    float acc = 0.f;
    int k0 = b * 64;
    for (int k = k0; k < k0 + 64; ++k) acc += x[k] * W[(size_t)k * 128 + cc];
    if (b == 0) acc += (t < 128) ? ba1[cc] : bg1[cc];
    atomicAdd(&bias1[t], acc);
    return;
  }
  b -= 8;
  if (b < 2) { int n = b * 256 + t; bias2[n] = ba2[n] - bg2[n]; return; }
  b -= 2;
  {
    int i = b * 256 + t;
    int p = positions[i], f = i >> 11;
    if (p > 0) atomicAdd(&counts[f * 2], 1);
    else if (p < 0) atomicAdd(&counts[f * 2 + 1], 1);
  }
}

// =====================================================================
// bf16 MFMA GEMM, 128x128, BK=32, XOR-swizzled LDS (slot = q ^ ((row>>1)&3)):
// staging source picks swizzled k-group so ds_read_b128 bank profile is uniform.
// epi 1: +bias,relu ; epi 3: +bias + fused per-row sum-of-squares -> tension.
// =====================================================================
__global__ __launch_bounds__(256) void gemm_bt(
    const u16* __restrict__ A, int lda,
    const u16* __restrict__ Bt, int ldb,
    u16* __restrict__ C, int ldc,
    const float* __restrict__ bias, int epi, int K,
    float* __restrict__ tension) {
  __shared__ __align__(16) u16 As[128 * 32];
  __shared__ __align__(16) u16 Bs[128 * 32];
  const int tid = threadIdx.x;
  const int m0 = blockIdx.x * 128;
  const int n0 = blockIdx.y * 128;
  f32x4 acc[4][4] = {};
  const int lane = tid & 63;
  const int w = tid >> 6;
  const int mw = (w & 1) * 64, nw = (w >> 1) * 64;
  const int fr = lane & 15;
  const int q = lane >> 4;
  const int ar0 = tid >> 2;                     // rows 0..63 (chunk tid), +64 for chunk tid+256
  const int ag = ((tid & 3) ^ ((ar0 >> 1) & 3)) * 8;  // (row+64)>>1 keeps same &3 -> ag reused

  for (int kk = 0; kk < K; kk += 32) {
    __syncthreads();
    __builtin_amdgcn_global_load_lds(AS1(A + (size_t)(m0 + ar0) * lda + kk + ag), AS3(&As[tid * 8]), 16, 0, 0);
    __builtin_amdgcn_global_load_lds(AS1(A + (size_t)(m0 + ar0 + 64) * lda + kk + ag), AS3(&As[(tid + 256) * 8]), 16, 0, 0);
    __builtin_amdgcn_global_load_lds(AS1(Bt + (size_t)(n0 + ar0) * ldb + kk + ag), AS3(&Bs[tid * 8]), 16, 0, 0);
    __builtin_amdgcn_global_load_lds(AS1(Bt + (size_t)(n0 + ar0 + 64) * ldb + kk + ag), AS3(&Bs[(tid + 256) * 8]), 16, 0, 0);
    __syncthreads();
    bf16x8 af[4], bfv[4];
#pragma unroll
    for (int mt = 0; mt < 4; ++mt) {
      int r = mw + mt * 16 + fr;
      af[mt] = *reinterpret_cast<const bf16x8*>(&As[r * 32 + ((q ^ ((r >> 1) & 3)) * 8)]);
    }
#pragma unroll
    for (int nt = 0; nt < 4; ++nt) {
      int r = nw + nt * 16 + fr;
      bfv[nt] = *reinterpret_cast<const bf16x8*>(&Bs[r * 32 + ((q ^ ((r >> 1) & 3)) * 8)]);
    }
#pragma unroll
    for (int mt = 0; mt < 4; ++mt)
#pragma unroll
      for (int nt = 0; nt < 4; ++nt)
        acc[mt][nt] = __builtin_amdgcn_mfma_f32_16x16x32_bf16(af[mt], bfv[nt], acc[mt][nt], 0, 0, 0);
  }
  const int rq = q * 4;  // D: col=lane&15, row=rq+reg [m89]
#pragma unroll
  for (int mt = 0; mt < 4; ++mt) {
    float srow[4] = {0.f, 0.f, 0.f, 0.f};
#pragma unroll
    for (int nt = 0; nt < 4; ++nt) {
      int col = n0 + nw + nt * 16 + fr;
      f32x4 v = acc[mt][nt];
#pragma unroll
      for (int r = 0; r < 4; ++r) {
        int row = m0 + mw + mt * 16 + rq + r;
        float val = v[r] + bias[col];
        if (epi == 1) val = val > 0.f ? val : 0.f;
        else srow[r] += val * val;
        C[(size_t)row * ldc + col] = f2bf(val);
      }
    }
    if (epi == 3) {
#pragma unroll
      for (int r = 0; r < 4; ++r) {
        float s = srow[r];
        s += __shfl_xor(s, 1, 16); s += __shfl_xor(s, 2, 16);
        s += __shfl_xor(s, 4, 16); s += __shfl_xor(s, 8, 16);
        if (fr == 0) atomicAdd(&tension[m0 + mw + mt * 16 + rq + r], s);
      }
    }
  }
}

// =====================================================================
// Fused GRU GEMM+gates. 512 threads / 8 waves, 128 rows x 64 hid-cols,
// 4 regions (r,z,gi_n,gh_n), acc 64 regs/thread. Phase loop FULLY unrolled
// so the gated-region acc index is compile-time. Swizzled LDS.
// =====================================================================
__global__ __launch_bounds__(512, 4) void gemm_gru(
    const u16* __restrict__ outbf, const u16* __restrict__ hidc,
    const u16* __restrict__ WgruT,
    const float* __restrict__ W_ihf, const float* __restrict__ bihf,
    const float* __restrict__ bhhf, const float* __restrict__ wealthf,
    const float* __restrict__ tension, u16* __restrict__ hpre) {
  __shared__ __align__(16) u16 As[128 * 32];
  __shared__ __align__(16) u16 Bs[3][64 * 32];
  const int tid = threadIdx.x;
  const int m0 = blockIdx.x * 128;
  const int j0 = blockIdx.y * 64;
  f32x4 acc[4][2][2] = {};  // [region][mt][nt]
  const int lane = tid & 63;
  const int w = tid >> 6;
  const int mw = (w & 3) * 32, nw = (w >> 2) * 32;
  const int fr = lane & 15;
  const int q = lane >> 4;
  // A staging: 512 chunks (128 rows x 4 slots), chunk = tid
  const int arow = tid >> 2;
  const int ag = ((tid & 3) ^ ((arow >> 1) & 3)) * 8;
  // B staging: 256 chunks/region (64 rows x 4 slots)
  const int ct = tid & 255;
  const int brow = ct >> 2;
  const int bg = ((ct & 3) ^ ((brow >> 1) & 3)) * 8;
  const int bsel = tid >> 8;  // wave-uniform

#pragma unroll
  for (int phase = 0; phase < 2; ++phase) {
    const u16* Ap = phase ? hidc : outbf;
    const int lda = phase ? 1024 : 512;
    const int kbeg = phase ? 512 : 0;
    const int kend = phase ? 1536 : 512;
    const int growG = phase ? 3072 : 2048;
#pragma unroll 1
    for (int kk = kbeg; kk < kend; kk += 32) {
      const int ka = kk - kbeg;
      __syncthreads();
      __builtin_amdgcn_global_load_lds(AS1(Ap + (size_t)(m0 + arow) * lda + ka + ag), AS3(&As[tid * 8]), 16, 0, 0);
      if (bsel == 0) {
        __builtin_amdgcn_global_load_lds(AS1(WgruT + (size_t)(j0 + brow) * 1536 + kk + bg), AS3(&Bs[0][ct * 8]), 16, 0, 0);
        __builtin_amdgcn_global_load_lds(AS1(WgruT + (size_t)(growG + j0 + brow) * 1536 + kk + bg), AS3(&Bs[2][ct * 8]), 16, 0, 0);
      } else {
        __builtin_amdgcn_global_load_lds(AS1(WgruT + (size_t)(1024 + j0 + brow) * 1536 + kk + bg), AS3(&Bs[1][ct * 8]), 16, 0, 0);
      }
      __syncthreads();
      bf16x8 af[2], b0[2], b1[2], b2[2];
#pragma unroll
      for (int mt = 0; mt < 2; ++mt) {
        int r = mw + mt * 16 + fr;
        af[mt] = *reinterpret_cast<const bf16x8*>(&As[r * 32 + ((q ^ ((r >> 1) & 3)) * 8)]);
      }
#pragma unroll
      for (int nt = 0; nt < 2; ++nt) {
        int r = nw + nt * 16 + fr;
        int s = (q ^ ((r >> 1) & 3)) * 8;
        b0[nt] = *reinterpret_cast<const bf16x8*>(&Bs[0][r * 32 + s]);
        b1[nt] = *reinterpret_cast<const bf16x8*>(&Bs[1][r * 32 + s]);
        b2[nt] = *reinterpret_cast<const bf16x8*>(&Bs[2][r * 32 + s]);
      }
#pragma unroll
      for (int mt = 0; mt < 2; ++mt)
#pragma unroll
        for (int nt = 0; nt < 2; ++nt) {
          acc[0][mt][nt] = __builtin_amdgcn_mfma_f32_16x16x32_bf16(af[mt], b0[nt], acc[0][mt][nt], 0, 0, 0);
          acc[1][mt][nt] = __builtin_amdgcn_mfma_f32_16x16x32_bf16(af[mt], b1[nt], acc[1][mt][nt], 0, 0, 0);
          if (phase == 0)
            acc[2][mt][nt] = __builtin_amdgcn_mfma_f32_16x16x32_bf16(af[mt], b2[nt], acc[2][mt][nt], 0, 0, 0);
          else
            acc[3][mt][nt] = __builtin_amdgcn_mfma_f32_16x16x32_bf16(af[mt], b2[nt], acc[3][mt][nt], 0, 0, 0);
        }
    }
  }

  // epilogue: D col=lane&15, row=(lane>>4)*4+reg [m89]
  const int rq = q * 4;
  const float* wt = W_ihf + (size_t)512 * 3072;  // tension row
  float wtr[2], wtz[2], wtn[2], bir[2], biz[2], bin_[2], bhr_[2], bhz_[2], bhn_[2];
#pragma unroll
  for (int nt = 0; nt < 2; ++nt) {
    int j = j0 + nw + nt * 16 + fr;
    wtr[nt] = wt[j]; wtz[nt] = wt[1024 + j]; wtn[nt] = wt[2048 + j];
    bir[nt] = bihf[j]; biz[nt] = bihf[1024 + j]; bin_[nt] = bihf[2048 + j];
    bhr_[nt] = bhhf[j]; bhz_[nt] = bhhf[1024 + j]; bhn_[nt] = bhhf[2048 + j];
  }
#pragma unroll
  for (int mt = 0; mt < 2; ++mt) {
#pragma unroll
    for (int rr = 0; rr < 4; ++rr) {
      int row = m0 + mw + mt * 16 + rq + rr;
      float tv = tension[row] * (1.f / 512.f);
      float wl = fminf(fmaxf(wealthf[row], 0.1f), 2.0f);
      float mod = 0.9f + 0.1f * wl;
#pragma unroll
      for (int nt = 0; nt < 2; ++nt) {
        int j = j0 + nw + nt * 16 + fr;
        float r = sigm(acc[0][mt][nt][rr] + tv * wtr[nt] + bir[nt] + bhr_[nt]);
        float z = sigm(acc[1][mt][nt][rr] + tv * wtz[nt] + biz[nt] + bhz_[nt]);
        float n = fast_tanh(acc[2][mt][nt][rr] + tv * wtn[nt] + bin_[nt]
                            + r * (acc[3][mt][nt][rr] + bhn_[nt]));
        float h = bf2f(hidc[(size_t)row * 1024 + j]);
        float h2 = (1.f - z) * n + z * h;
        h2 = fminf(fmaxf(h2 * mod, -10.f), 10.f);
        hpre[(size_t)row * 1024 + j] = f2bf(h2);
      }
    }
  }
}

// =====================================================================
__global__ void stats_kernel(const u16* __restrict__ hpre, const int* __restrict__ positions,
                             float* __restrict__ fsums) {
  int cc = blockIdx.x, f = blockIdx.y, z = blockIdx.z, t = threadIdx.x;
  int col = cc * 128 + (t & 127);
  int half = t >> 7;
  float st = 0, sp = 0, sm = 0;
  for (int it = 0; it < 128; ++it) {
    int row = (f << 11) + ((z * 128 + it) << 1) + half;
    int p = positions[row];
    float v = bf2f(hpre[(size_t)row * 1024 + col]);
    st += v;
    if (p > 0) sp += v;
    if (p < 0) sm += v;
  }
  atomicAdd(&fsums[(f * 3 + 0) * 1024 + col], st);
  atomicAdd(&fsums[(f * 3 + 1) * 1024 + col], sp);
  atomicAdd(&fsums[(f * 3 + 2) * 1024 + col], sm);
}

__global__ void derive_kernel(const float* __restrict__ fsums, const int* __restrict__ counts,
                              float* __restrict__ mean1, float* __restrict__ mean2,
                              float* __restrict__ fmean, float* __restrict__ gop,
                              float* __restrict__ scal) {
  int c = threadIdx.x;  // 1024
  int cnt1 = 0, cnt2 = 0, cf1[8], cf2[8];
#pragma unroll
  for (int f = 0; f < 8; ++f) {
    cf1[f] = counts[f * 2]; cf2[f] = counts[f * 2 + 1];
    cnt1 += cf1[f]; cnt2 += cf2[f];
  }
  float s1 = 0, s2 = 0;
#pragma unroll
  for (int f = 0; f < 8; ++f) { s1 += fsums[(f * 3 + 1) * 1024 + c]; s2 += fsums[(f * 3 + 2) * 1024 + c]; }
  float m1 = s1 / (float)(cnt1 > 1 ? cnt1 : 1);
  float m2 = s2 / (float)(cnt2 > 1 ? cnt2 : 1);
  float a1 = (cnt1 >= 2) ? 0.1f : 0.f;
  float a2 = (cnt2 >= 2) ? 0.1f : 0.f;
  float g = 0;
#pragma unroll
  for (int f = 0; f < 8; ++f) {
    float fm = (fsums[(f * 3) * 1024 + c]
                + a1 * ((float)cf1[f] * m1 - fsums[(f * 3 + 1) * 1024 + c])
                + a2 * ((float)cf2[f] * m2 - fsums[(f * 3 + 2) * 1024 + c])) * (1.f / 2048.f);
    fmean[f * 1024 + c] = fm;
    g += fm;
  }
  gop[c] = g * 0.125f;
  mean1[c] = m1; mean2[c] = m2;
  if (c == 0) { scal[0] = a1; scal[1] = a2; }
}

__global__ void finalize_kernel(const u16* __restrict__ hpre, const int* __restrict__ positions,
                                const int* __restrict__ step, const float* __restrict__ mean1,
                                const float* __restrict__ mean2, const float* __restrict__ fmean,
                                const float* __restrict__ gop, const float* __restrict__ scal,
                                float* __restrict__ out) {
  int row = blockIdx.x, t = threadIdx.x;
  int p = positions[row];
  float w1 = (p > 0) ? scal[0] : 0.f;
  float w2 = (p < 0) ? scal[1] : 0.f;
  int f = row >> 11, q = row & 2047;
  bool deb = (step[0] > 5) && (q < 512);
  const u16* hrow = hpre + (size_t)row * 1024;
  const float* fmp = fmean + f * 1024;
  float* orow = out + 513 + (size_t)row * 1024;
#pragma unroll
  for (int e = 0; e < 8; ++e) {
    int c = e * 128 + t;
    float h = bf2f(hrow[c]);
    float hgs = h + w1 * (mean1[c] - h) + w2 * (mean2[c] - h);
    float hfs = 0.85f * hgs + 0.15f * fmp[c];
    orow[c] = deb ? (0.85f * hfs + 0.15f * gop[c]) : hfs;
  }
}

__global__ void softmax_kernel(const float* __restrict__ tension, float* __restrict__ weights,
                               float* __restrict__ out) {
  __shared__ float red[1024];
  int t = threadIdx.x;
  float tv[16], mx = -1e30f, sumt = 0.f;
#pragma unroll
  for (int k = 0; k < 16; ++k) {
    tv[k] = tension[t + k * 1024] * (1.f / 512.f);
    mx = fmaxf(mx, tv[k]); sumt += tv[k];
  }
  red[t] = mx; __syncthreads();
  for (int s = 512; s > 0; s >>= 1) { if (t < s) red[t] = fmaxf(red[t], red[t + s]); __syncthreads(); }
  float m = red[0]; __syncthreads();
  red[t] = sumt; __syncthreads();
  for (int s = 512; s > 0; s >>= 1) { if (t < s) red[t] += red[t + s]; __syncthreads(); }
  float tot = red[0]; __syncthreads();
  float ev[16], se = 0.f;
#pragma unroll
  for (int k = 0; k < 16; ++k) { ev[k] = __expf(tv[k] - m); se += ev[k]; }
  red[t] = se; __syncthreads();
  for (int s = 512; s > 0; s >>= 1) { if (t < s) red[t] += red[t + s]; __syncthreads(); }
  float invS = 1.f / red[0];
#pragma unroll
  for (int k = 0; k < 16; ++k) weights[t + k * 1024] = ev[k] * invS;
  if (t == 0) out[512] = tot * (1.f / 16384.f);
}

__global__ void wsum_kernel(const float* __restrict__ weights, const u16* __restrict__ outbf,
                            float* __restrict__ co) {
  int b = blockIdx.x, t = threadIdx.x;
  int c = t * 2;
  float a0 = 0.f, a1 = 0.f;
  int i0 = b * 128;
  for (int i = i0; i < i0 + 128; ++i) {
    float w = weights[i];
    unsigned v = *reinterpret_cast<const unsigned*>(outbf + (size_t)i * 512 + c);
    a0 += w * bf2f(v & 0xffff);
    a1 += w * bf2f(v >> 16);
  }
  atomicAdd(&co[c], a0);
  atomicAdd(&co[c + 1], a1);
}

__global__ void pred_kernel(const float* __restrict__ co, const float* __restrict__ Wof,
                            const float* __restrict__ bof, float* __restrict__ out) {
  __shared__ float cs[512];
  int t = threadIdx.x, n = blockIdx.x * 256 + t;
  cs[t] = co[t]; cs[t + 256] = co[t + 256];
  __syncthreads();
  float acc = bof[n];
  for (int ck = 0; ck < 512; ++ck) acc += cs[ck] * Wof[(size_t)ck * 512 + n];
  out[n] = acc;
}

// =====================================================================
extern "C" void kernel_launch(void* const* d_in, const int* in_sizes, int n_in,
                              void* d_out, int out_size, void* d_ws, size_t ws_size,
                              hipStream_t stream) {
  const float* x      = (const float*)d_in[0];
  const float* hid    = (const float*)d_in[1];
  const float* wealth = (const float*)d_in[2];
  const float* Wa1    = (const float*)d_in[3];
  const float* ba1    = (const float*)d_in[4];
  const float* Wa2    = (const float*)d_in[5];
  const float* ba2    = (const float*)d_in[6];
  const float* Wg1    = (const float*)d_in[7];
  const float* bg1    = (const float*)d_in[8];
  const float* Wg2    = (const float*)d_in[9];
  const float* bg2    = (const float*)d_in[10];
  const float* W_ih   = (const float*)d_in[11];
  const float* W_hh   = (const float*)d_in[12];
  const float* b_ih   = (const float*)d_in[13];
  const float* b_hh   = (const float*)d_in[14];
  const float* Wo     = (const float*)d_in[15];
  const float* bo     = (const float*)d_in[16];
  const int* positions= (const int*)d_in[17];
  const int* step     = (const int*)d_in[18];
  float* out = (float*)d_out;  // [0,512) pred | [512] avg_tension | [513..) new_h

  char* w = (char*)d_ws;
  size_t off = 0;
  auto alloc = [&](size_t bytes) { void* p = w + off; off += (bytes + 255) & ~(size_t)255; return p; };
  u16*   hidc    = (u16*)  alloc((size_t)NC * 1024 * 2);
  u16*   outbf   = (u16*)  alloc((size_t)NC * 512 * 2);
  u16*   hpre    = (u16*)  alloc((size_t)NC * 1024 * 2);
  u16*   WgruT   = (u16*)  alloc((size_t)4096 * 1536 * 2);
  u16*   W1catT  = (u16*)  alloc((size_t)256 * 1024 * 2);
  u16*   W2catT  = (u16*)  alloc((size_t)512 * 256 * 2);
  u16*   t1      = (u16*)  alloc((size_t)NC * 256 * 2);
  // zeroed contiguous: bias1 | co | counts | fsums | tension
  float* bias1   = (float*)alloc(256 * 4);
  float* co      = (float*)alloc(512 * 4);
  int*   counts  = (int*)  alloc(16 * 4);
  float* fsums   = (float*)alloc(8 * 3 * 1024 * 4);
  float* tension = (float*)alloc(NC * 4);
  float* bias2   = (float*)alloc(512 * 4);
  float* weights = (float*)alloc(NC * 4);
  float* mean1   = (float*)alloc(1024 * 4);
  float* mean2   = (float*)alloc(1024 * 4);
  float* gop     = (float*)alloc(1024 * 4);
  float* fmean   = (float*)alloc(8 * 1024 * 4);
  float* scal    = (float*)alloc(8 * 4);

  hipMemsetAsync(bias1, 0, 1024 + 2048 + 256 + 98304 + 65536, stream);

  // cvt (16384) + packT (1248) + smalls (74)
  prep_kernel<<<17706, 256, 0, stream>>>(hid, hidc, W_ih, W_hh, WgruT,
                                         Wa1, Wg1, W1catT, Wa2, Wg2, W2catT,
                                         x, ba1, bg1, bias1, ba2, bg2, bias2,
                                         positions, counts);

  // t1 = relu(h @ W1 + bias1)   M=16384 K=1024 N=256
  gemm_bt<<<dim3(128, 2), 256, 0, stream>>>(hidc, 1024, W1catT, 1024, t1, 256,
                                            bias1, 1, 1024, nullptr);
  // output = t1 @ [Wa2;-Wg2] + (ba2-bg2); fused tension
  gemm_bt<<<dim3(128, 4), 256, 0, stream>>>(t1, 256, W2catT, 256, outbf, 512,
                                            bias2, 3, 256, tension);

  // fused GRU (128x64 tiles, 2048 blocks, 512 threads)
  gemm_gru<<<dim3(128, 16), 512, 0, stream>>>(outbf, hidc, WgruT, W_ih, b_ih, b_hh,
                                              wealth, tension, hpre);

  stats_kernel<<<dim3(8, 8, 8), 256, 0, stream>>>(hpre, positions, fsums);
  derive_kernel<<<1, 1024, 0, stream>>>(fsums, counts, mean1, mean2, fmean, gop, scal);
  finalize_kernel<<<NC, 128, 0, stream>>>(hpre, positions, step, mean1, mean2, fmean, gop,
                                          scal, out);

  softmax_kernel<<<1, 1024, 0, stream>>>(tension, weights, out);
  wsum_kernel<<<128, 256, 0, stream>>>(weights, outbf, co);
  pred_kernel<<<2, 256, 0, stream>>>(co, Wo, bo, out);

  (void)in_sizes; (void)n_in; (void)out_size; (void)ws_size;
}